// Round 7
// baseline (222.873 us; speedup 1.0000x reference)
//
#include <hip/hip_runtime.h>
#include <hip/hip_bf16.h>

typedef unsigned short u16;
typedef unsigned char  u8;

#define D_KEY   128
#define BANK_N  9720
#define BANK_P  9728   /* 76*128 */
#define N_TOK   1620
#define N_PAD   1664   /* 13*128 */
#define OBJ_N   3
#define M_PAD   1664
#define LDCOL   1664
#define ONES_ROW 1539  /* vm row of 1.0 -> PV computes lsum as C row 1539 */
#define QK_SCALE 0.08838834764831845f
#define KITERS  76     /* BANK_P / 128 */
#define QK_BLOCKS 988  /* 13 * 76 */

typedef __bf16 bf16x8 __attribute__((ext_vector_type(8)));
typedef float  f32x4  __attribute__((ext_vector_type(4)));
typedef unsigned int u32x4 __attribute__((ext_vector_type(4)));
typedef int i32x8 __attribute__((ext_vector_type(8)));

__device__ __forceinline__ float bf2f(u16 u) {
  union { unsigned int i; float f; } v; v.i = ((unsigned int)u) << 16; return v.f;
}
__device__ __forceinline__ u16 f2bf(float f) {
  unsigned int x = __float_as_uint(f);
  unsigned int r = x + 0x7fffu + ((x >> 16) & 1u);  // RNE
  return (u16)(r >> 16);
}
__device__ __forceinline__ unsigned pack_fp8x4(float a, float b, float c, float d) {
  unsigned v = __builtin_amdgcn_cvt_pk_fp8_f32(a, b, 0, false);
  v = __builtin_amdgcn_cvt_pk_fp8_f32(c, d, v, true);
  return v;
}
__device__ __forceinline__ u8 f2fp8(float a) {
  return (u8)(__builtin_amdgcn_cvt_pk_fp8_f32(a, 0.f, 0, false) & 0xff);
}

__device__ __forceinline__ void load_lds16(const void* g, void* l) {
  __builtin_amdgcn_global_load_lds(
      (const __attribute__((address_space(1))) void*)g,
      (__attribute__((address_space(3))) void*)l, 16, 0, 0);
}

__device__ __forceinline__ i32x8 ldfrag_g(const u8* p) {
  u32x4 lo = *(const u32x4*)p;
  u32x4 hi = *(const u32x4*)(p + 16);
  return (i32x8){(int)lo[0], (int)lo[1], (int)lo[2], (int)lo[3],
                 (int)hi[0], (int)hi[1], (int)hi[2], (int)hi[3]};
}

// ---- prep: qT transpose (0..51) + keys transpose (52..355) ----
__global__ void prep(const float* __restrict__ q, const float* __restrict__ keys,
                     u16* __restrict__ qT, u16* __restrict__ kT) {
  __shared__ float t[64][65];
  int b = blockIdx.x;
  const int tx = threadIdx.x & 63;
  const int ty = threadIdx.x >> 6;
  if (b < 52) {                                    // qT: [128][N_TOK] -> [N_PAD][128]
    const int bd = (b & 1) * 64;                   // d-tile
    const int bn = (b >> 1) * 64;                  // n-tile (26 tiles -> 1664 rows)
#pragma unroll
    for (int i = 0; i < 64; i += 4) {
      int d = bd + ty + i;
      int n = bn + tx;
      t[ty + i][tx] = (n < N_TOK) ? q[(size_t)d * N_TOK + n] : 0.f;
    }
    __syncthreads();
#pragma unroll
    for (int i = 0; i < 64; i += 4) {
      int r = ty + i;                              // n within tile
      qT[(size_t)(bn + r) * D_KEY + bd + tx] = f2bf(t[tx][r] * QK_SCALE);
    }
    return;
  }
  // keys transpose: 152 x 2 tiles
  b -= 52;
  const int bk = (b % 152) * 64;
  const int bd = (b / 152) * 64;
#pragma unroll
  for (int i = 0; i < 64; i += 4) {
    int d = bd + ty + i;
    int k = bk + tx;
    t[ty + i][tx] = (k < BANK_N) ? keys[(size_t)d * BANK_N + k] : 0.f;
  }
  __syncthreads();
#pragma unroll
  for (int i = 0; i < 64; i += 4) {
    int r = ty + i;
    kT[(size_t)(bk + r) * D_KEY + bd + tx] = f2bf(t[tx][r]);
  }
}

// ---- QK GEMM (blocks 0..987) + vm8 fp8 cast (blocks 988..4939) in ONE dispatch ----
__global__ void gemm_qk_vm(const u16* __restrict__ A, const u16* __restrict__ B,
                           u8* __restrict__ E8,
                           const float* __restrict__ values,
                           const float* __restrict__ masks,
                           u8* __restrict__ vm8)
{
  __shared__ __align__(16) u16 sbuf[8192];    // 16 KB: As 8K + Bs 8K; E8-stage aliases all

  if (blockIdx.x >= QK_BLOCKS) {
    // ---- vm8: fp8 cast, 16 bytes/thread (4x float4 loads = 64 B contiguous) ----
    const int NV = BANK_P / 16;                    // 608
    int idx = (blockIdx.x - QK_BLOCKS) * 256 + threadIdx.x;
    if (idx >= M_PAD * NV) return;
    int m = idx / NV;
    int k16 = (idx - m * NV) * 16;
    const bool ones = (m == ONES_ROW);
    const float* src = nullptr;
    if (m < 1536)          src = values + (size_t)m * BANK_N;
    else if (m < ONES_ROW) src = masks + (size_t)(m - 1536) * BANK_N;
    u32x4 outv;
#pragma unroll
    for (int c = 0; c < 4; c++) {
      int k4 = k16 + c * 4;
      float4 v = make_float4(0.f, 0.f, 0.f, 0.f);
      if (ones) {
        v.x = (k4     < BANK_N) ? 1.f : 0.f;
        v.y = (k4 + 1 < BANK_N) ? 1.f : 0.f;
        v.z = (k4 + 2 < BANK_N) ? 1.f : 0.f;
        v.w = (k4 + 3 < BANK_N) ? 1.f : 0.f;
      } else if (src) {
        if (k4 + 3 < BANK_N) v = *(const float4*)(src + k4);
        else {
          if (k4     < BANK_N) v.x = src[k4];
          if (k4 + 1 < BANK_N) v.y = src[k4 + 1];
          if (k4 + 2 < BANK_N) v.z = src[k4 + 2];
          if (k4 + 3 < BANK_N) v.w = src[k4 + 3];
        }
      }
      outv[c] = pack_fp8x4(v.x, v.y, v.z, v.w);
    }
    *(u32x4*)(vm8 + (size_t)m * BANK_P + k16) = outv;
    return;
  }

  // ---- QK GEMM: E8[n][k] = fp8(exp(qT.kT)); pad cols -> 0 ----
  u16* As = sbuf;
  u16* Bs = sbuf + 4096;

  const int tid  = threadIdx.x;
  const int wave = tid >> 6;
  const int lane = tid & 63;
  const int bn = blockIdx.x % 76, bm = blockIdx.x / 76;

  const u16* Abase = A + (size_t)bm * 128 * D_KEY;
  const u16* Bbase = B + (size_t)bn * 128 * D_KEY;

  const int r  = lane >> 2;
  const int c8 = (lane & 3) << 3;
  const int s0 = wave, s1 = wave + 4;

  f32x4 acc[4][4];
#pragma unroll
  for (int i = 0; i < 4; i++)
#pragma unroll
    for (int j = 0; j < 4; j++) acc[i][j] = (f32x4){0.f, 0.f, 0.f, 0.f};

  const int m_in = lane & 15;
  const int quad = lane >> 4;
  const int wm = (wave >> 1) * 64;
  const int wn = (wave & 1) * 64;

  for (int kt = 0; kt < D_KEY; kt += 32) {
    load_lds16(Abase + (size_t)(s0 * 16 + r) * D_KEY + kt + c8, &As[s0 * 512]);
    load_lds16(Abase + (size_t)(s1 * 16 + r) * D_KEY + kt + c8, &As[s1 * 512]);
    load_lds16(Bbase + (size_t)(s0 * 16 + r) * D_KEY + kt + c8, &Bs[s0 * 512]);
    load_lds16(Bbase + (size_t)(s1 * 16 + r) * D_KEY + kt + c8, &Bs[s1 * 512]);
    __syncthreads();

    bf16x8 af[4], bfr[4];
#pragma unroll
    for (int i = 0; i < 4; i++)
      af[i] = *(const bf16x8*)&As[(wm + i * 16 + m_in) * 32 + quad * 8];
#pragma unroll
    for (int j = 0; j < 4; j++)
      bfr[j] = *(const bf16x8*)&Bs[(wn + j * 16 + m_in) * 32 + quad * 8];
#pragma unroll
    for (int i = 0; i < 4; i++)
#pragma unroll
      for (int j = 0; j < 4; j++)
        acc[i][j] = __builtin_amdgcn_mfma_f32_16x16x32_bf16(af[i], bfr[j], acc[i][j], 0, 0, 0);
    __syncthreads();
  }

  // exp -> fp8, zero pad cols; stage 16KB in LDS; coalesced store
  u8* sb8 = (u8*)sbuf;
#pragma unroll
  for (int i = 0; i < 4; i++)
#pragma unroll
    for (int j = 0; j < 4; j++)
#pragma unroll
      for (int t = 0; t < 4; t++) {
        int row_l = wm + i * 16 + quad * 4 + t;   // D layout: col=lane&15, row=quad*4+t [m89]
        int col_l = wn + j * 16 + m_in;
        bool valid = (bn * 128 + col_l) < BANK_N;
        sb8[(row_l << 7) + col_l] = valid ? f2fp8(__expf(acc[i][j][t])) : (u8)0;
      }
  __syncthreads();

  for (int chunk = tid; chunk < 1024; chunk += 256) {
    int row = chunk >> 3;
    int cu  = (chunk & 7) << 4;
    u32x4 v = *(const u32x4*)&sb8[(row << 7) + cu];
    *(u32x4*)&E8[(size_t)(bm * 128 + row) * BANK_P + bn * 128 + cu] = v;
  }
}

// ---- PV GEMM (R7 hybrid): A (vm8) staged via 16 KB LDS + shared by all waves;
// B (E8) fragments read DIRECT global->VGPR (32 contiguous bytes/lane, per-j to
// cap live VGPRs). Halves the barrier-drained bytes/iter, moves B traffic onto
// async per-wave loads covered by cross-block TLP, halves LDS (16 KB) removing
// the LDS residency cap, halves bank-conflict exposure. R3's failure (both
// operands direct, no barriers) doesn't apply: A keeps sharing + cadence.
// C-store no longer nontemporal -> memC L3-retained for lsum/epilogue.
__global__ __launch_bounds__(256, 3)
void gemm_pv(const u8* __restrict__ A, const u8* __restrict__ B,
             u16* __restrict__ memC, int nParts, size_t cPartStride)
{
  __shared__ __align__(16) u16 sbuf[8192];    // 16 KB: A sub-tiles; C-stage aliases
  u8* As8 = (u8*)sbuf;

  const int tid  = threadIdx.x;
  const int wave = tid >> 6;
  const int lane = tid & 63;

  // T1 bijective XCD chunk swizzle (m204 form; handles gridDim.x % 8 != 0)
  const int bq = (int)gridDim.x >> 3, br = (int)gridDim.x & 7;
  const int xcd = blockIdx.x & 7, bj = blockIdx.x >> 3;
  int b = (xcd < br ? xcd * (bq + 1) : br * (bq + 1) + (xcd - br) * bq) + bj;

  int bz = b / 169;
  int rr = b - bz * 169;
  int gid = rr / 52;
  int rem = rr - gid * 52;
  int width = (gid < 3) ? 4 : 1;
  int bm = rem / width;
  int bn = gid * 4 + (rem - bm * width);

  // uneven K-split: KITERS = base*nParts + remP; first remP parts get base+1
  const int base = KITERS / nParts;
  const int remP = KITERS - base * nParts;
  const int nt    = base + (bz < remP ? 1 : 0);
  const int itbeg = bz * base + (bz < remP ? bz : remP);
  const int kbeg  = itbeg * 128;

  const u8* Abase = A + (size_t)bm * 128 * BANK_P;

  const int srow  = lane >> 1;
  const int shalf = (((lane & 1) ^ ((lane >> 3) & 1)) << 4);

  f32x4 acc[4][4];
#pragma unroll
  for (int i = 0; i < 4; i++)
#pragma unroll
    for (int j = 0; j < 4; j++) acc[i][j] = (f32x4){0.f, 0.f, 0.f, 0.f};

  const int m_in = lane & 15;
  const int quad = lane >> 4;
  const int wm = (wave >> 1) * 64;
  const int wn = (wave & 1) * 64;
  const int fxor = ((m_in >> 2) & 1) << 4;

  const size_t arow_off = (size_t)(wave * 32 + srow) * BANK_P;

  // per-lane direct B row pointers (row = bn*128 + wn + j*16 + m_in)
  const u8* pb[4];
#pragma unroll
  for (int j = 0; j < 4; j++)
    pb[j] = B + (size_t)(bn * 128 + wn + j * 16 + m_in) * BANK_P + kbeg + quad * 32;

  for (int it = 0; it < nt; ++it) {
    const int kt = kbeg + it * 128;
    const int koff = it * 128;
#pragma unroll
    for (int s = 0; s < 4; s++)
      load_lds16(Abase + arow_off + kt + s * 32 + shalf, As8 + s * 4096 + wave * 1024);
    __syncthreads();

    i32x8 a8[4];
#pragma unroll
    for (int i = 0; i < 4; i++) {
      const u8* p = As8 + quad * 4096 + (wm + i * 16 + m_in) * 32;
      u32x4 lo = *(const u32x4*)(p + fxor);
      u32x4 hi = *(const u32x4*)(p + (fxor ^ 16));
      a8[i] = (i32x8){(int)lo[0], (int)lo[1], (int)lo[2], (int)lo[3],
                      (int)hi[0], (int)hi[1], (int)hi[2], (int)hi[3]};
    }
#pragma unroll
    for (int j = 0; j < 4; j++) {
      i32x8 b8 = ldfrag_g(pb[j] + koff);
#pragma unroll
      for (int i = 0; i < 4; i++)
        acc[i][j] = __builtin_amdgcn_mfma_scale_f32_16x16x128_f8f6f4(
            a8[i], b8, acc[i][j], 0, 0,              // cbsz=fp8, blgp=fp8
            0, 0x7f7f7f7f, 0, 0x7f7f7f7f);           // unit scales (E8M0 127 = x1)
    }
    __syncthreads();
  }

  // C-stage in two 16-KB halves (rows 0-63 by waves 0,1; rows 64-127 by waves 2,3)
  u16* Cg = memC + (size_t)bz * cPartStride;
#pragma unroll
  for (int h = 0; h < 2; h++) {
    __syncthreads();
    if ((wave >> 1) == h) {
#pragma unroll
      for (int i = 0; i < 4; i++)
#pragma unroll
        for (int j = 0; j < 4; j++)
#pragma unroll
          for (int t = 0; t < 4; t++) {
            int row_l = i * 16 + quad * 4 + t;      // row within half
            int col_l = wn + j * 16 + m_in;
            sbuf[(row_l << 7) + col_l] = f2bf(acc[i][j][t]);
          }
    }
    __syncthreads();
    for (int chunk = tid; chunk < 1024; chunk += 256) {
      int row = chunk >> 4;                         // 0..63
      int cu  = (chunk & 15) << 3;
      u32x4 v = *(const u32x4*)&sbuf[(row << 7) + cu];
      *(u32x4*)&Cg[(size_t)(bm * 128 + h * 64 + row) * LDCOL + bn * 128 + cu] = v;
    }
  }
}

// ---- epilogue: vec4 over n; lsum from memC row ONES_ROW (L2/L3-broadcast) ----
__global__ void epilogue(const u16* __restrict__ memC, const float* __restrict__ q_out,
                         float* __restrict__ out, int nParts) {
  const int NV = N_TOK / 4;                     // 405
  int idx = blockIdx.x * 256 + threadIdx.x;
  if (idx >= OBJ_N * 1024 * NV) return;
  int n4 = (idx % NV) * 4;
  int t = idx / NV;
  int c = t & 1023;
  int o = t >> 10;
  const size_t ps = (size_t)M_PAD * LDCOL;

  const u16* lbase = memC + (size_t)ONES_ROW * LDCOL + n4;
  float4 l = make_float4(0.f, 0.f, 0.f, 0.f);
  for (int z = 0; z < nParts; z++) {
    ushort4 v = *(const ushort4*)(lbase + z * ps);
    l.x += bf2f(v.x); l.y += bf2f(v.y); l.z += bf2f(v.z); l.w += bf2f(v.w);
  }

  size_t rowoff = (c < 512) ? (size_t)(o * 512 + c) * LDCOL
                            : (size_t)(1536 + o) * LDCOL;
  const u16* base = memC + rowoff + n4;
  float4 s = make_float4(0.f, 0.f, 0.f, 0.f);
  for (int z = 0; z < nParts; z++) {
    ushort4 v = *(const ushort4*)(base + z * ps);
    s.x += bf2f(v.x); s.y += bf2f(v.y); s.z += bf2f(v.z); s.w += bf2f(v.w);
  }
  float4 rv;
  float ix = 1.f / l.x, iy = 1.f / l.y, iz = 1.f / l.z, iw = 1.f / l.w;
  if (c < 512) {
    rv.x = s.x * ix; rv.y = s.y * iy; rv.z = s.z * iz; rv.w = s.w * iw;
  } else {
    float4 q = *(const float4*)(q_out + (size_t)(o * 512 + (c - 512)) * N_TOK + n4);
    rv.x = q.x * s.x * ix; rv.y = q.y * s.y * iy;
    rv.z = q.z * s.z * iz; rv.w = q.w * s.w * iw;
  }
  *(float4*)(out + (size_t)(o * 1024 + c) * N_TOK + n4) = rv;
}

extern "C" void kernel_launch(void* const* d_in, const int* in_sizes, int n_in,
                              void* d_out, int out_size, void* d_ws, size_t ws_size,
                              hipStream_t stream) {
  const float* keys   = (const float*)d_in[0];
  const float* q_in   = (const float*)d_in[1];
  const float* q_out  = (const float*)d_in[2];
  const float* values = (const float*)d_in[3];
  const float* masks  = (const float*)d_in[4];
  float* out = (float*)d_out;

  char* ws = (char*)d_ws;
  size_t off = 0;
  auto alloc = [&](size_t bytes) -> void* {
    void* p = ws + off; off += (bytes + 255) & ~(size_t)255; return p;
  };
  u16* qT  = (u16*)alloc((size_t)N_PAD * D_KEY * 2);
  u16* kT  = (u16*)alloc((size_t)BANK_P * D_KEY * 2);
  u8*  vm8 = (u8*)alloc((size_t)M_PAD * BANK_P);
  u8*  E8  = (u8*)alloc((size_t)N_PAD * BANK_P);

  int nParts = 8;
  while (nParts > 1 && off + (size_t)nParts * M_PAD * LDCOL * 2 > ws_size) nParts >>= 1;
  u16* memC = (u16*)alloc((size_t)nParts * M_PAD * LDCOL * 2);

  prep<<<356, 256, 0, stream>>>(q_in, keys, qT, kT);

  const int vmBlocks = (M_PAD * (BANK_P / 16) + 255) / 256;   // 3952
  gemm_qk_vm<<<QK_BLOCKS + vmBlocks, 256, 0, stream>>>(qT, kT, E8, values, masks, vm8);

  gemm_pv<<<dim3(169 * nParts), 256, 0, stream>>>(vm8, E8, memC, nParts, (size_t)M_PAD * LDCOL);

  epilogue<<<(OBJ_N * 1024 * (N_TOK / 4) + 255) / 256, 256, 0, stream>>>(
      memC, q_out, out, nParts);
}

// Round 8
// 194.026 us; speedup vs baseline: 1.1487x; 1.1487x over previous
//
#include <hip/hip_runtime.h>
#include <hip/hip_bf16.h>

typedef unsigned short u16;
typedef unsigned char  u8;

#define D_KEY   128
#define BANK_N  9720
#define BANK_P  9728   /* 76*128 */
#define N_TOK   1620
#define N_PAD   1664   /* 13*128 */
#define OBJ_N   3
#define M_PAD   1664
#define LDCOL   1664
#define ONES_ROW 1539  /* vm row of 1.0 -> PV computes lsum as C row 1539 */
#define QK_SCALE 0.08838834764831845f
#define KITERS  76     /* BANK_P / 128 */
#define QK_BLOCKS 988  /* 13 * 76 */

typedef __bf16 bf16x8 __attribute__((ext_vector_type(8)));
typedef float  f32x4  __attribute__((ext_vector_type(4)));
typedef unsigned int u32x4 __attribute__((ext_vector_type(4)));
typedef int i32x8 __attribute__((ext_vector_type(8)));

__device__ __forceinline__ float bf2f(u16 u) {
  union { unsigned int i; float f; } v; v.i = ((unsigned int)u) << 16; return v.f;
}
__device__ __forceinline__ u16 f2bf(float f) {
  unsigned int x = __float_as_uint(f);
  unsigned int r = x + 0x7fffu + ((x >> 16) & 1u);  // RNE
  return (u16)(r >> 16);
}
__device__ __forceinline__ unsigned pack_fp8x4(float a, float b, float c, float d) {
  unsigned v = __builtin_amdgcn_cvt_pk_fp8_f32(a, b, 0, false);
  v = __builtin_amdgcn_cvt_pk_fp8_f32(c, d, v, true);
  return v;
}
__device__ __forceinline__ u8 f2fp8(float a) {
  return (u8)(__builtin_amdgcn_cvt_pk_fp8_f32(a, 0.f, 0, false) & 0xff);
}

__device__ __forceinline__ void load_lds16(const void* g, void* l) {
  __builtin_amdgcn_global_load_lds(
      (const __attribute__((address_space(1))) void*)g,
      (__attribute__((address_space(3))) void*)l, 16, 0, 0);
}

// ---- prep: qT transpose (0..51) + keys transpose (52..355) ----
__global__ void prep(const float* __restrict__ q, const float* __restrict__ keys,
                     u16* __restrict__ qT, u16* __restrict__ kT) {
  __shared__ float t[64][65];
  int b = blockIdx.x;
  const int tx = threadIdx.x & 63;
  const int ty = threadIdx.x >> 6;
  if (b < 52) {                                    // qT: [128][N_TOK] -> [N_PAD][128]
    const int bd = (b & 1) * 64;                   // d-tile
    const int bn = (b >> 1) * 64;                  // n-tile (26 tiles -> 1664 rows)
#pragma unroll
    for (int i = 0; i < 64; i += 4) {
      int d = bd + ty + i;
      int n = bn + tx;
      t[ty + i][tx] = (n < N_TOK) ? q[(size_t)d * N_TOK + n] : 0.f;
    }
    __syncthreads();
#pragma unroll
    for (int i = 0; i < 64; i += 4) {
      int r = ty + i;                              // n within tile
      qT[(size_t)(bn + r) * D_KEY + bd + tx] = f2bf(t[tx][r] * QK_SCALE);
    }
    return;
  }
  // keys transpose: 152 x 2 tiles
  b -= 52;
  const int bk = (b % 152) * 64;
  const int bd = (b / 152) * 64;
#pragma unroll
  for (int i = 0; i < 64; i += 4) {
    int d = bd + ty + i;
    int k = bk + tx;
    t[ty + i][tx] = (k < BANK_N) ? keys[(size_t)d * BANK_N + k] : 0.f;
  }
  __syncthreads();
#pragma unroll
  for (int i = 0; i < 64; i += 4) {
    int r = ty + i;
    kT[(size_t)(bk + r) * D_KEY + bd + tx] = f2bf(t[tx][r]);
  }
}

// ---- QK GEMM (blocks 0..987) + vm8 fp8 cast (blocks 988..4939) in ONE dispatch ----
__global__ void gemm_qk_vm(const u16* __restrict__ A, const u16* __restrict__ B,
                           u8* __restrict__ E8,
                           const float* __restrict__ values,
                           const float* __restrict__ masks,
                           u8* __restrict__ vm8)
{
  __shared__ __align__(16) u16 sbuf[8192];    // 16 KB: As 8K + Bs 8K; E8-stage aliases all

  if (blockIdx.x >= QK_BLOCKS) {
    // ---- vm8: fp8 cast, 16 bytes/thread (4x float4 loads = 64 B contiguous) ----
    const int NV = BANK_P / 16;                    // 608
    int idx = (blockIdx.x - QK_BLOCKS) * 256 + threadIdx.x;
    if (idx >= M_PAD * NV) return;
    int m = idx / NV;
    int k16 = (idx - m * NV) * 16;
    const bool ones = (m == ONES_ROW);
    const float* src = nullptr;
    if (m < 1536)          src = values + (size_t)m * BANK_N;
    else if (m < ONES_ROW) src = masks + (size_t)(m - 1536) * BANK_N;
    u32x4 outv;
#pragma unroll
    for (int c = 0; c < 4; c++) {
      int k4 = k16 + c * 4;
      float4 v = make_float4(0.f, 0.f, 0.f, 0.f);
      if (ones) {
        v.x = (k4     < BANK_N) ? 1.f : 0.f;
        v.y = (k4 + 1 < BANK_N) ? 1.f : 0.f;
        v.z = (k4 + 2 < BANK_N) ? 1.f : 0.f;
        v.w = (k4 + 3 < BANK_N) ? 1.f : 0.f;
      } else if (src) {
        if (k4 + 3 < BANK_N) v = *(const float4*)(src + k4);
        else {
          if (k4     < BANK_N) v.x = src[k4];
          if (k4 + 1 < BANK_N) v.y = src[k4 + 1];
          if (k4 + 2 < BANK_N) v.z = src[k4 + 2];
          if (k4 + 3 < BANK_N) v.w = src[k4 + 3];
        }
      }
      outv[c] = pack_fp8x4(v.x, v.y, v.z, v.w);
    }
    *(u32x4*)(vm8 + (size_t)m * BANK_P + k16) = outv;
    return;
  }

  // ---- QK GEMM: E8[n][k] = fp8(exp(qT.kT)); pad cols -> 0 ----
  u16* As = sbuf;
  u16* Bs = sbuf + 4096;

  const int tid  = threadIdx.x;
  const int wave = tid >> 6;
  const int lane = tid & 63;
  const int bn = blockIdx.x % 76, bm = blockIdx.x / 76;

  const u16* Abase = A + (size_t)bm * 128 * D_KEY;
  const u16* Bbase = B + (size_t)bn * 128 * D_KEY;

  const int r  = lane >> 2;
  const int c8 = (lane & 3) << 3;
  const int s0 = wave, s1 = wave + 4;

  f32x4 acc[4][4];
#pragma unroll
  for (int i = 0; i < 4; i++)
#pragma unroll
    for (int j = 0; j < 4; j++) acc[i][j] = (f32x4){0.f, 0.f, 0.f, 0.f};

  const int m_in = lane & 15;
  const int quad = lane >> 4;
  const int wm = (wave >> 1) * 64;
  const int wn = (wave & 1) * 64;

  for (int kt = 0; kt < D_KEY; kt += 32) {
    load_lds16(Abase + (size_t)(s0 * 16 + r) * D_KEY + kt + c8, &As[s0 * 512]);
    load_lds16(Abase + (size_t)(s1 * 16 + r) * D_KEY + kt + c8, &As[s1 * 512]);
    load_lds16(Bbase + (size_t)(s0 * 16 + r) * D_KEY + kt + c8, &Bs[s0 * 512]);
    load_lds16(Bbase + (size_t)(s1 * 16 + r) * D_KEY + kt + c8, &Bs[s1 * 512]);
    __syncthreads();

    bf16x8 af[4], bfr[4];
#pragma unroll
    for (int i = 0; i < 4; i++)
      af[i] = *(const bf16x8*)&As[(wm + i * 16 + m_in) * 32 + quad * 8];
#pragma unroll
    for (int j = 0; j < 4; j++)
      bfr[j] = *(const bf16x8*)&Bs[(wn + j * 16 + m_in) * 32 + quad * 8];
#pragma unroll
    for (int i = 0; i < 4; i++)
#pragma unroll
      for (int j = 0; j < 4; j++)
        acc[i][j] = __builtin_amdgcn_mfma_f32_16x16x32_bf16(af[i], bfr[j], acc[i][j], 0, 0, 0);
    __syncthreads();
  }

  // exp -> fp8, zero pad cols; stage 16KB in LDS; coalesced store
  u8* sb8 = (u8*)sbuf;
#pragma unroll
  for (int i = 0; i < 4; i++)
#pragma unroll
    for (int j = 0; j < 4; j++)
#pragma unroll
      for (int t = 0; t < 4; t++) {
        int row_l = wm + i * 16 + quad * 4 + t;   // D layout: col=lane&15, row=quad*4+t [m89]
        int col_l = wn + j * 16 + m_in;
        bool valid = (bn * 128 + col_l) < BANK_N;
        sb8[(row_l << 7) + col_l] = valid ? f2fp8(__expf(acc[i][j][t])) : (u8)0;
      }
  __syncthreads();

  for (int chunk = tid; chunk < 1024; chunk += 256) {
    int row = chunk >> 3;
    int cu  = (chunk & 7) << 4;
    u32x4 v = *(const u32x4*)&sb8[(row << 7) + cu];
    *(u32x4*)&E8[(size_t)(bm * 128 + row) * BANK_P + bn * 128 + cu] = v;
  }
}

// ---- PV GEMM (R8): R4 full-LDS body + DEPTH-2 counted-vmcnt pipeline (T3+T4).
// 2x32KB LDS buffers. Steady state per iter: compute buf[t&1] -> B1 barrier
// (all reads of buf[t&1] done) -> issue stage(t+2) into buf[t&1] ->
// s_waitcnt vmcnt(8) (waits ONLY tile t+1's 8 loads, issued a full iteration
// ago; t+2's 8 stay in flight across both barriers) -> B2 barrier -> swap.
// No vmcnt(0) in steady state. This differs from failed R1 (depth-1: waited
// same-iter loads) and failed R3/R7 (no LDS sharing). T5 setprio on MFMAs.
__global__ __launch_bounds__(256, 2)
void gemm_pv(const u8* __restrict__ A, const u8* __restrict__ B,
             u16* __restrict__ memC, int nParts, size_t cPartStride)
{
  __shared__ __align__(16) u16 sbuf[32768];   // 64 KB: 2 x (A 16K + B 16K)
  u8* const lds0 = (u8*)sbuf;

  const int tid  = threadIdx.x;
  const int wave = tid >> 6;
  const int lane = tid & 63;

  // T1 bijective XCD chunk swizzle (m204 form; handles gridDim.x % 8 != 0)
  const int bq = (int)gridDim.x >> 3, br = (int)gridDim.x & 7;
  const int xcd = blockIdx.x & 7, bj = blockIdx.x >> 3;
  int b = (xcd < br ? xcd * (bq + 1) : br * (bq + 1) + (xcd - br) * bq) + bj;

  int bz = b / 169;
  int rr = b - bz * 169;
  int gid = rr / 52;
  int rem = rr - gid * 52;
  int width = (gid < 3) ? 4 : 1;
  int bm = rem / width;
  int bn = gid * 4 + (rem - bm * width);

  // uneven K-split: KITERS = base*nParts + remP; first remP parts get base+1
  const int base = KITERS / nParts;
  const int remP = KITERS - base * nParts;
  const int nt    = base + (bz < remP ? 1 : 0);   // >= 9 for nParts <= 8
  const int itbeg = bz * base + (bz < remP ? bz : remP);
  const int kbeg  = itbeg * 128;

  const u8* Abase = A + (size_t)bm * 128 * BANK_P;
  const u8* Bbase = B + (size_t)bn * 128 * BANK_P;

  const int srow  = lane >> 1;
  const int shalf = (((lane & 1) ^ ((lane >> 3) & 1)) << 4);
  const size_t arow_off = (size_t)(wave * 32 + srow) * BANK_P;

  f32x4 acc[4][4];
#pragma unroll
  for (int i = 0; i < 4; i++)
#pragma unroll
    for (int j = 0; j < 4; j++) acc[i][j] = (f32x4){0.f, 0.f, 0.f, 0.f};

  const int m_in = lane & 15;
  const int quad = lane >> 4;
  const int wm = (wave >> 1) * 64;
  const int wn = (wave & 1) * 64;
  const int fxor = ((m_in >> 2) & 1) << 4;

  // stage tile -> buffer q: 8 global_load_lds (16B) per wave
  auto stage = [&](int tile, int q) {
    const int kt = kbeg + tile * 128;
    u8* dst = lds0 + q * 32768;
#pragma unroll
    for (int s = 0; s < 4; s++)
      load_lds16(Abase + arow_off + kt + s * 32 + shalf, dst + s * 4096 + wave * 1024);
#pragma unroll
    for (int s = 0; s < 4; s++)
      load_lds16(Bbase + arow_off + kt + s * 32 + shalf, dst + 16384 + s * 4096 + wave * 1024);
  };

  // prologue: tiles 0 and 1 in flight; wait only tile 0 (oldest 8)
  stage(0, 0);
  stage(1, 1);
  asm volatile("s_waitcnt vmcnt(8)" ::: "memory");
  __builtin_amdgcn_s_barrier();
  __builtin_amdgcn_sched_barrier(0);

  for (int t = 0; t < nt; ++t) {
    const u8* As8 = lds0 + (t & 1) * 32768;
    const u8* Bs8 = As8 + 16384;

    __builtin_amdgcn_s_setprio(1);
    i32x8 a8[4];
#pragma unroll
    for (int i = 0; i < 4; i++) {
      const u8* p = As8 + quad * 4096 + (wm + i * 16 + m_in) * 32;
      u32x4 lo = *(const u32x4*)(p + fxor);
      u32x4 hi = *(const u32x4*)(p + (fxor ^ 16));
      a8[i] = (i32x8){(int)lo[0], (int)lo[1], (int)lo[2], (int)lo[3],
                      (int)hi[0], (int)hi[1], (int)hi[2], (int)hi[3]};
    }
#pragma unroll
    for (int j = 0; j < 4; j++) {
      const u8* p = Bs8 + quad * 4096 + (wn + j * 16 + m_in) * 32;
      u32x4 lo = *(const u32x4*)(p + fxor);
      u32x4 hi = *(const u32x4*)(p + (fxor ^ 16));
      i32x8 b8 = (i32x8){(int)lo[0], (int)lo[1], (int)lo[2], (int)lo[3],
                         (int)hi[0], (int)hi[1], (int)hi[2], (int)hi[3]};
#pragma unroll
      for (int i = 0; i < 4; i++)
        acc[i][j] = __builtin_amdgcn_mfma_scale_f32_16x16x128_f8f6f4(
            a8[i], b8, acc[i][j], 0, 0,              // cbsz=fp8, blgp=fp8
            0, 0x7f7f7f7f, 0, 0x7f7f7f7f);           // unit scales (E8M0 127 = x1)
    }
    __builtin_amdgcn_s_setprio(0);

    if (t + 1 >= nt) break;                          // all waves exit together

    __builtin_amdgcn_sched_barrier(0);
    __builtin_amdgcn_s_barrier();                    // B1: buf[t&1] reads done
    if (t + 2 < nt) {
      stage(t + 2, t & 1);
      asm volatile("s_waitcnt vmcnt(8)" ::: "memory");   // retire tile t+1's loads
    } else {
      asm volatile("s_waitcnt vmcnt(0)" ::: "memory");   // drain before last tile
    }
    __builtin_amdgcn_s_barrier();                    // B2: buf[(t+1)&1] ready
    __builtin_amdgcn_sched_barrier(0);
  }

  __syncthreads();

  // C-stage in two 16-KB halves (rows 0-63 by waves 0,1; rows 64-127 by waves 2,3)
  u16* Cg = memC + (size_t)bz * cPartStride;
#pragma unroll
  for (int h = 0; h < 2; h++) {
    __syncthreads();
    if ((wave >> 1) == h) {
#pragma unroll
      for (int i = 0; i < 4; i++)
#pragma unroll
        for (int j = 0; j < 4; j++)
#pragma unroll
          for (int t = 0; t < 4; t++) {
            int row_l = i * 16 + quad * 4 + t;      // row within half
            int col_l = wn + j * 16 + m_in;
            sbuf[(row_l << 7) + col_l] = f2bf(acc[i][j][t]);
          }
    }
    __syncthreads();
    for (int chunk = tid; chunk < 1024; chunk += 256) {
      int row = chunk >> 4;                         // 0..63
      int cu  = (chunk & 15) << 3;
      u32x4 v = *(const u32x4*)&sbuf[(row << 7) + cu];
      *(u32x4*)&Cg[(size_t)(bm * 128 + h * 64 + row) * LDCOL + bn * 128 + cu] = v;
    }
  }
}

// ---- epilogue: vec4 over n; lsum from memC row ONES_ROW (L2/L3-broadcast) ----
__global__ void epilogue(const u16* __restrict__ memC, const float* __restrict__ q_out,
                         float* __restrict__ out, int nParts) {
  const int NV = N_TOK / 4;                     // 405
  int idx = blockIdx.x * 256 + threadIdx.x;
  if (idx >= OBJ_N * 1024 * NV) return;
  int n4 = (idx % NV) * 4;
  int t = idx / NV;
  int c = t & 1023;
  int o = t >> 10;
  const size_t ps = (size_t)M_PAD * LDCOL;

  const u16* lbase = memC + (size_t)ONES_ROW * LDCOL + n4;
  float4 l = make_float4(0.f, 0.f, 0.f, 0.f);
  for (int z = 0; z < nParts; z++) {
    ushort4 v = *(const ushort4*)(lbase + z * ps);
    l.x += bf2f(v.x); l.y += bf2f(v.y); l.z += bf2f(v.z); l.w += bf2f(v.w);
  }

  size_t rowoff = (c < 512) ? (size_t)(o * 512 + c) * LDCOL
                            : (size_t)(1536 + o) * LDCOL;
  const u16* base = memC + rowoff + n4;
  float4 s = make_float4(0.f, 0.f, 0.f, 0.f);
  for (int z = 0; z < nParts; z++) {
    ushort4 v = *(const ushort4*)(base + z * ps);
    s.x += bf2f(v.x); s.y += bf2f(v.y); s.z += bf2f(v.z); s.w += bf2f(v.w);
  }
  float4 rv;
  float ix = 1.f / l.x, iy = 1.f / l.y, iz = 1.f / l.z, iw = 1.f / l.w;
  if (c < 512) {
    rv.x = s.x * ix; rv.y = s.y * iy; rv.z = s.z * iz; rv.w = s.w * iw;
  } else {
    float4 q = *(const float4*)(q_out + (size_t)(o * 512 + (c - 512)) * N_TOK + n4);
    rv.x = q.x * s.x * ix; rv.y = q.y * s.y * iy;
    rv.z = q.z * s.z * iz; rv.w = q.w * s.w * iw;
  }
  *(float4*)(out + (size_t)(o * 1024 + c) * N_TOK + n4) = rv;
}

extern "C" void kernel_launch(void* const* d_in, const int* in_sizes, int n_in,
                              void* d_out, int out_size, void* d_ws, size_t ws_size,
                              hipStream_t stream) {
  const float* keys   = (const float*)d_in[0];
  const float* q_in   = (const float*)d_in[1];
  const float* q_out  = (const float*)d_in[2];
  const float* values = (const float*)d_in[3];
  const float* masks  = (const float*)d_in[4];
  float* out = (float*)d_out;

  char* ws = (char*)d_ws;
  size_t off = 0;
  auto alloc = [&](size_t bytes) -> void* {
    void* p = ws + off; off += (bytes + 255) & ~(size_t)255; return p;
  };
  u16* qT  = (u16*)alloc((size_t)N_PAD * D_KEY * 2);
  u16* kT  = (u16*)alloc((size_t)BANK_P * D_KEY * 2);
  u8*  vm8 = (u8*)alloc((size_t)M_PAD * BANK_P);
  u8*  E8  = (u8*)alloc((size_t)N_PAD * BANK_P);

  int nParts = 8;
  while (nParts > 1 && off + (size_t)nParts * M_PAD * LDCOL * 2 > ws_size) nParts >>= 1;
  u16* memC = (u16*)alloc((size_t)nParts * M_PAD * LDCOL * 2);

  prep<<<356, 256, 0, stream>>>(q_in, keys, qT, kT);

  const int vmBlocks = (M_PAD * (BANK_P / 16) + 255) / 256;   // 3952
  gemm_qk_vm<<<QK_BLOCKS + vmBlocks, 256, 0, stream>>>(qT, kT, E8, values, masks, vm8);

  gemm_pv<<<dim3(169 * nParts), 256, 0, stream>>>(vm8, E8, memC, nParts, (size_t)M_PAD * LDCOL);

  epilogue<<<(OBJ_N * 1024 * (N_TOK / 4) + 255) / 256, 256, 0, stream>>>(
      memC, q_out, out, nParts);
}

// Round 9
// 189.005 us; speedup vs baseline: 1.1792x; 1.0266x over previous
//
#include <hip/hip_runtime.h>
#include <hip/hip_bf16.h>

typedef unsigned short u16;
typedef unsigned char  u8;

#define D_KEY   128
#define BANK_N  9720
#define BANK_P  9728   /* 76*128 */
#define N_TOK   1620
#define N_PAD   1664   /* 13*128 */
#define OBJ_N   3
#define M_PAD   1664
#define LDCOL   1664
#define ONES_ROW 1539  /* vm row of 1.0 -> PV computes lsum as C row 1539 */
#define QK_SCALE 0.08838834764831845f
#define KITERS  76     /* BANK_P / 128 */
#define QK_BLOCKS 988  /* 13 * 76 */

typedef __bf16 bf16x8 __attribute__((ext_vector_type(8)));
typedef float  f32x4  __attribute__((ext_vector_type(4)));
typedef float  f32x16 __attribute__((ext_vector_type(16)));
typedef unsigned int u32x4 __attribute__((ext_vector_type(4)));
typedef int i32x8 __attribute__((ext_vector_type(8)));

__device__ __forceinline__ float bf2f(u16 u) {
  union { unsigned int i; float f; } v; v.i = ((unsigned int)u) << 16; return v.f;
}
__device__ __forceinline__ u16 f2bf(float f) {
  unsigned int x = __float_as_uint(f);
  unsigned int r = x + 0x7fffu + ((x >> 16) & 1u);  // RNE
  return (u16)(r >> 16);
}
__device__ __forceinline__ unsigned pack_fp8x4(float a, float b, float c, float d) {
  unsigned v = __builtin_amdgcn_cvt_pk_fp8_f32(a, b, 0, false);
  v = __builtin_amdgcn_cvt_pk_fp8_f32(c, d, v, true);
  return v;
}
__device__ __forceinline__ u8 f2fp8(float a) {
  return (u8)(__builtin_amdgcn_cvt_pk_fp8_f32(a, 0.f, 0, false) & 0xff);
}

__device__ __forceinline__ void load_lds16(const void* g, void* l) {
  __builtin_amdgcn_global_load_lds(
      (const __attribute__((address_space(1))) void*)g,
      (__attribute__((address_space(3))) void*)l, 16, 0, 0);
}

// ---- prep: qT transpose (0..51) + keys transpose (52..355) ----
__global__ void prep(const float* __restrict__ q, const float* __restrict__ keys,
                     u16* __restrict__ qT, u16* __restrict__ kT) {
  __shared__ float t[64][65];
  int b = blockIdx.x;
  const int tx = threadIdx.x & 63;
  const int ty = threadIdx.x >> 6;
  if (b < 52) {                                    // qT: [128][N_TOK] -> [N_PAD][128]
    const int bd = (b & 1) * 64;                   // d-tile
    const int bn = (b >> 1) * 64;                  // n-tile (26 tiles -> 1664 rows)
#pragma unroll
    for (int i = 0; i < 64; i += 4) {
      int d = bd + ty + i;
      int n = bn + tx;
      t[ty + i][tx] = (n < N_TOK) ? q[(size_t)d * N_TOK + n] : 0.f;
    }
    __syncthreads();
#pragma unroll
    for (int i = 0; i < 64; i += 4) {
      int r = ty + i;                              // n within tile
      qT[(size_t)(bn + r) * D_KEY + bd + tx] = f2bf(t[tx][r] * QK_SCALE);
    }
    return;
  }
  // keys transpose: 152 x 2 tiles
  b -= 52;
  const int bk = (b % 152) * 64;
  const int bd = (b / 152) * 64;
#pragma unroll
  for (int i = 0; i < 64; i += 4) {
    int d = bd + ty + i;
    int k = bk + tx;
    t[ty + i][tx] = (k < BANK_N) ? keys[(size_t)d * BANK_N + k] : 0.f;
  }
  __syncthreads();
#pragma unroll
  for (int i = 0; i < 64; i += 4) {
    int r = ty + i;
    kT[(size_t)(bk + r) * D_KEY + bd + tx] = f2bf(t[tx][r]);
  }
}

// ---- QK GEMM (blocks 0..987) + vm8 fp8 cast (blocks 988..4939) in ONE dispatch ----
__global__ void gemm_qk_vm(const u16* __restrict__ A, const u16* __restrict__ B,
                           u8* __restrict__ E8,
                           const float* __restrict__ values,
                           const float* __restrict__ masks,
                           u8* __restrict__ vm8)
{
  __shared__ __align__(16) u16 sbuf[8192];    // 16 KB: As 8K + Bs 8K; E8-stage aliases all

  if (blockIdx.x >= QK_BLOCKS) {
    // ---- vm8: fp8 cast, 16 bytes/thread (4x float4 loads = 64 B contiguous) ----
    const int NV = BANK_P / 16;                    // 608
    int idx = (blockIdx.x - QK_BLOCKS) * 256 + threadIdx.x;
    if (idx >= M_PAD * NV) return;
    int m = idx / NV;
    int k16 = (idx - m * NV) * 16;
    const bool ones = (m == ONES_ROW);
    const float* src = nullptr;
    if (m < 1536)          src = values + (size_t)m * BANK_N;
    else if (m < ONES_ROW) src = masks + (size_t)(m - 1536) * BANK_N;
    u32x4 outv;
#pragma unroll
    for (int c = 0; c < 4; c++) {
      int k4 = k16 + c * 4;
      float4 v = make_float4(0.f, 0.f, 0.f, 0.f);
      if (ones) {
        v.x = (k4     < BANK_N) ? 1.f : 0.f;
        v.y = (k4 + 1 < BANK_N) ? 1.f : 0.f;
        v.z = (k4 + 2 < BANK_N) ? 1.f : 0.f;
        v.w = (k4 + 3 < BANK_N) ? 1.f : 0.f;
      } else if (src) {
        if (k4 + 3 < BANK_N) v = *(const float4*)(src + k4);
        else {
          if (k4     < BANK_N) v.x = src[k4];
          if (k4 + 1 < BANK_N) v.y = src[k4 + 1];
          if (k4 + 2 < BANK_N) v.z = src[k4 + 2];
          if (k4 + 3 < BANK_N) v.w = src[k4 + 3];
        }
      }
      outv[c] = pack_fp8x4(v.x, v.y, v.z, v.w);
    }
    *(u32x4*)(vm8 + (size_t)m * BANK_P + k16) = outv;
    return;
  }

  // ---- QK GEMM: E8[n][k] = fp8(exp(qT.kT)); pad cols -> 0 ----
  u16* As = sbuf;
  u16* Bs = sbuf + 4096;

  const int tid  = threadIdx.x;
  const int wave = tid >> 6;
  const int lane = tid & 63;
  const int bn = blockIdx.x % 76, bm = blockIdx.x / 76;

  const u16* Abase = A + (size_t)bm * 128 * D_KEY;
  const u16* Bbase = B + (size_t)bn * 128 * D_KEY;

  const int r  = lane >> 2;
  const int c8 = (lane & 3) << 3;
  const int s0 = wave, s1 = wave + 4;

  f32x4 acc[4][4];
#pragma unroll
  for (int i = 0; i < 4; i++)
#pragma unroll
    for (int j = 0; j < 4; j++) acc[i][j] = (f32x4){0.f, 0.f, 0.f, 0.f};

  const int m_in = lane & 15;
  const int quad = lane >> 4;
  const int wm = (wave >> 1) * 64;
  const int wn = (wave & 1) * 64;

  for (int kt = 0; kt < D_KEY; kt += 32) {
    load_lds16(Abase + (size_t)(s0 * 16 + r) * D_KEY + kt + c8, &As[s0 * 512]);
    load_lds16(Abase + (size_t)(s1 * 16 + r) * D_KEY + kt + c8, &As[s1 * 512]);
    load_lds16(Bbase + (size_t)(s0 * 16 + r) * D_KEY + kt + c8, &Bs[s0 * 512]);
    load_lds16(Bbase + (size_t)(s1 * 16 + r) * D_KEY + kt + c8, &Bs[s1 * 512]);
    __syncthreads();

    bf16x8 af[4], bfr[4];
#pragma unroll
    for (int i = 0; i < 4; i++)
      af[i] = *(const bf16x8*)&As[(wm + i * 16 + m_in) * 32 + quad * 8];
#pragma unroll
    for (int j = 0; j < 4; j++)
      bfr[j] = *(const bf16x8*)&Bs[(wn + j * 16 + m_in) * 32 + quad * 8];
#pragma unroll
    for (int i = 0; i < 4; i++)
#pragma unroll
      for (int j = 0; j < 4; j++)
        acc[i][j] = __builtin_amdgcn_mfma_f32_16x16x32_bf16(af[i], bfr[j], acc[i][j], 0, 0, 0);
    __syncthreads();
  }

  // exp -> fp8, zero pad cols; stage 16KB in LDS; coalesced store
  u8* sb8 = (u8*)sbuf;
#pragma unroll
  for (int i = 0; i < 4; i++)
#pragma unroll
    for (int j = 0; j < 4; j++)
#pragma unroll
      for (int t = 0; t < 4; t++) {
        int row_l = wm + i * 16 + quad * 4 + t;   // D layout: col=lane&15, row=quad*4+t [m89]
        int col_l = wn + j * 16 + m_in;
        bool valid = (bn * 128 + col_l) < BANK_N;
        sb8[(row_l << 7) + col_l] = valid ? f2fp8(__expf(acc[i][j][t])) : (u8)0;
      }
  __syncthreads();

  for (int chunk = tid; chunk < 1024; chunk += 256) {
    int row = chunk >> 3;
    int cu  = (chunk & 7) << 4;
    u32x4 v = *(const u32x4*)&sb8[(row << 7) + cu];
    *(u32x4*)&E8[(size_t)(bm * 128 + row) * BANK_P + bn * 128 + cu] = v;
  }
}

// ---- PV GEMM (R9): BK=64 + mfma_scale_f32_32x32x64_f8f6f4 so the DOUBLE
// buffer fits in 32 KB (2 x (A 8K + B 8K)) -> occupancy stays ~4 blocks/CU
// (the R1/R8 killer was 64 KB) AND depth-2 counted vmcnt(4) pipelining works.
// Steady state: compute buf[t&1] -> B1 -> stage(t+2) into buf[t&1] ->
// vmcnt(4) (retires only tile t+1's 4 loads/wave) -> B2. No vmcnt(0) drain.
// LDS layout: 16B-unit swizzle u' = u ^ ((row>>1)&3) -> 64 lanes spread over
// all 32 banks at exactly 8 accesses/bank (derived + lane-checked). Write side
// uses pre-swizzled GLOBAL source with linear global_load_lds dest (rule #21).
// A/B frag: row=lane&31, k=(lane>>5)*32 (8 regs); C: col=lane&31,
// row=(reg&3)+8*(reg>>2)+4*(lane>>5) [m74/m101 HW-verified].
__global__ __launch_bounds__(256, 4)
void gemm_pv(const u8* __restrict__ A, const u8* __restrict__ B,
             u16* __restrict__ memC, int nParts, size_t cPartStride)
{
  __shared__ __align__(16) u16 sbuf[16384];   // 32 KB: 2 x (A 8K + B 8K); C-stage aliases
  u8* const lds0 = (u8*)sbuf;

  const int tid  = threadIdx.x;
  const int wave = tid >> 6;
  const int lane = tid & 63;

  // T1 bijective XCD chunk swizzle (m204 form; handles gridDim.x % 8 != 0)
  const int bq = (int)gridDim.x >> 3, br = (int)gridDim.x & 7;
  const int xcd = blockIdx.x & 7, bj = blockIdx.x >> 3;
  int b = (xcd < br ? xcd * (bq + 1) : br * (bq + 1) + (xcd - br) * bq) + bj;

  int bz = b / 169;
  int rr = b - bz * 169;
  int gid = rr / 52;
  int rem = rr - gid * 52;
  int width = (gid < 3) ? 4 : 1;
  int bm = rem / width;
  int bn = gid * 4 + (rem - bm * width);

  // uneven K-split over 128-wide super-iters; BK=64 doubles the iter count
  const int base = KITERS / nParts;
  const int remP = KITERS - base * nParts;
  const int nt128 = base + (bz < remP ? 1 : 0);
  const int itbeg = bz * base + (bz < remP ? bz : remP);
  const int kbeg  = itbeg * 128;
  const int kN    = nt128 * 2;                // #BK=64 iters (>= 18 at nParts=8)

  const u8* Abase = A + (size_t)bm * 128 * BANK_P;
  const u8* Bbase = B + (size_t)bn * 128 * BANK_P;

  f32x16 acc[2][2];
#pragma unroll
  for (int i = 0; i < 2; i++)
#pragma unroll
    for (int j = 0; j < 2; j++)
#pragma unroll
      for (int r = 0; r < 16; r++) acc[i][j][r] = 0.f;

  const int l31  = lane & 31;
  const int h    = lane >> 5;                 // k-half of the lane
  const int wm   = (wave >> 1) * 64;
  const int wn   = (wave & 1) * 64;

  // stage-side per-lane source swizzle: lane writes LDS unit (rowl, lane&3);
  // source global unit = (lane&3) ^ ((rowl>>1)&3)
  const int srow0 = wave * 32 + (lane >> 2);  // s=0 row; s=1 adds 16
  const int sswz0 = ((lane & 3) ^ ((srow0 >> 1) & 3)) << 4;
  const int srow1 = srow0 + 16;
  const int sswz1 = ((lane & 3) ^ ((srow1 >> 1) & 3)) << 4;
  const size_t soffA0 = (size_t)srow0 * BANK_P + sswz0;
  const size_t soffA1 = (size_t)srow1 * BANK_P + sswz1;

  // stage one BK=64 tile (A 8K + B 8K) into buffer q; 4 loads/wave
  auto stage = [&](int t64, int q) {
    const int kt = kbeg + t64 * 64;
    u8* dst = lds0 + q * 16384 + wave * 2048;
    load_lds16(Abase + soffA0 + kt, dst);
    load_lds16(Abase + soffA1 + kt, dst + 1024);
    load_lds16(Bbase + soffA0 + kt, dst + 8192);
    load_lds16(Bbase + soffA1 + kt, dst + 8192 + 1024);
  };

  // read-side unit positions for this lane (u = 2h, 2h+1; u' = u ^ s(row))
  // computed per-frag since s depends on row.

  // prologue: tiles 0,1 in flight; wait tile 0 only (4 newest outstanding)
  stage(0, 0);
  stage(1, 1);
  asm volatile("s_waitcnt vmcnt(4)" ::: "memory");
  __builtin_amdgcn_s_barrier();
  __builtin_amdgcn_sched_barrier(0);

  for (int t = 0; t < kN; ++t) {
    const u8* As8 = lds0 + (t & 1) * 16384;
    const u8* Bs8 = As8 + 8192;

    __builtin_amdgcn_s_setprio(1);
    i32x8 a8[2], b8[2];
#pragma unroll
    for (int m = 0; m < 2; m++) {
      const int row = wm + m * 32 + l31;
      const int s = (row >> 1) & 3;
      const u8* p = As8 + row * 64;
      u32x4 lo = *(const u32x4*)(p + (((2 * h)     ^ s) << 4));
      u32x4 hi = *(const u32x4*)(p + (((2 * h + 1) ^ s) << 4));
      a8[m] = (i32x8){(int)lo[0], (int)lo[1], (int)lo[2], (int)lo[3],
                      (int)hi[0], (int)hi[1], (int)hi[2], (int)hi[3]};
    }
#pragma unroll
    for (int n = 0; n < 2; n++) {
      const int row = wn + n * 32 + l31;
      const int s = (row >> 1) & 3;
      const u8* p = Bs8 + row * 64;
      u32x4 lo = *(const u32x4*)(p + (((2 * h)     ^ s) << 4));
      u32x4 hi = *(const u32x4*)(p + (((2 * h + 1) ^ s) << 4));
      b8[n] = (i32x8){(int)lo[0], (int)lo[1], (int)lo[2], (int)lo[3],
                      (int)hi[0], (int)hi[1], (int)hi[2], (int)hi[3]};
    }
#pragma unroll
    for (int n = 0; n < 2; n++)
#pragma unroll
      for (int m = 0; m < 2; m++)
        acc[m][n] = __builtin_amdgcn_mfma_scale_f32_32x32x64_f8f6f4(
            a8[m], b8[n], acc[m][n], 0, 0,           // cbsz=fp8, blgp=fp8
            0, 0x7f7f7f7f, 0, 0x7f7f7f7f);           // unit scales (E8M0 127 = x1)
    __builtin_amdgcn_s_setprio(0);

    if (t + 1 >= kN) break;

    __builtin_amdgcn_sched_barrier(0);
    __builtin_amdgcn_s_barrier();                    // B1: buf[t&1] reads done
    if (t + 2 < kN) {
      stage(t + 2, t & 1);
      asm volatile("s_waitcnt vmcnt(4)" ::: "memory");   // retire tile t+1's loads
    } else {
      asm volatile("s_waitcnt vmcnt(0)" ::: "memory");   // drain before last tile
    }
    __builtin_amdgcn_s_barrier();                    // B2: buf[(t+1)&1] ready
    __builtin_amdgcn_sched_barrier(0);
  }

  __syncthreads();

  // C-stage in two 16-KB halves (rows 0-63 by waves 0,1; rows 64-127 by 2,3)
  u16* Cg = memC + (size_t)bz * cPartStride;
#pragma unroll
  for (int hh = 0; hh < 2; hh++) {
    __syncthreads();
    if ((wave >> 1) == hh) {
#pragma unroll
      for (int m = 0; m < 2; m++)
#pragma unroll
        for (int n = 0; n < 2; n++)
#pragma unroll
          for (int r = 0; r < 16; r++) {
            int row_l = m * 32 + (r & 3) + 8 * (r >> 2) + 4 * h;  // 0..63
            int col_l = (wave & 1) * 64 + n * 32 + l31;
            sbuf[(row_l << 7) + col_l] = f2bf(acc[m][n][r]);
          }
    }
    __syncthreads();
    for (int chunk = tid; chunk < 1024; chunk += 256) {
      int row = chunk >> 4;                         // 0..63
      int cu  = (chunk & 15) << 3;
      u32x4 v = *(const u32x4*)&sbuf[(row << 7) + cu];
      *(u32x4*)&Cg[(size_t)(bm * 128 + hh * 64 + row) * LDCOL + bn * 128 + cu] = v;
    }
  }
}

// ---- epilogue: vec4 over n; lsum from memC row ONES_ROW (L2/L3-broadcast) ----
__global__ void epilogue(const u16* __restrict__ memC, const float* __restrict__ q_out,
                         float* __restrict__ out, int nParts) {
  const int NV = N_TOK / 4;                     // 405
  int idx = blockIdx.x * 256 + threadIdx.x;
  if (idx >= OBJ_N * 1024 * NV) return;
  int n4 = (idx % NV) * 4;
  int t = idx / NV;
  int c = t & 1023;
  int o = t >> 10;
  const size_t ps = (size_t)M_PAD * LDCOL;

  const u16* lbase = memC + (size_t)ONES_ROW * LDCOL + n4;
  float4 l = make_float4(0.f, 0.f, 0.f, 0.f);
  for (int z = 0; z < nParts; z++) {
    ushort4 v = *(const ushort4*)(lbase + z * ps);
    l.x += bf2f(v.x); l.y += bf2f(v.y); l.z += bf2f(v.z); l.w += bf2f(v.w);
  }

  size_t rowoff = (c < 512) ? (size_t)(o * 512 + c) * LDCOL
                            : (size_t)(1536 + o) * LDCOL;
  const u16* base = memC + rowoff + n4;
  float4 s = make_float4(0.f, 0.f, 0.f, 0.f);
  for (int z = 0; z < nParts; z++) {
    ushort4 v = *(const ushort4*)(base + z * ps);
    s.x += bf2f(v.x); s.y += bf2f(v.y); s.z += bf2f(v.z); s.w += bf2f(v.w);
  }
  float4 rv;
  float ix = 1.f / l.x, iy = 1.f / l.y, iz = 1.f / l.z, iw = 1.f / l.w;
  if (c < 512) {
    rv.x = s.x * ix; rv.y = s.y * iy; rv.z = s.z * iz; rv.w = s.w * iw;
  } else {
    float4 q = *(const float4*)(q_out + (size_t)(o * 512 + (c - 512)) * N_TOK + n4);
    rv.x = q.x * s.x * ix; rv.y = q.y * s.y * iy;
    rv.z = q.z * s.z * iz; rv.w = q.w * s.w * iw;
  }
  *(float4*)(out + (size_t)(o * 1024 + c) * N_TOK + n4) = rv;
}

extern "C" void kernel_launch(void* const* d_in, const int* in_sizes, int n_in,
                              void* d_out, int out_size, void* d_ws, size_t ws_size,
                              hipStream_t stream) {
  const float* keys   = (const float*)d_in[0];
  const float* q_in   = (const float*)d_in[1];
  const float* q_out  = (const float*)d_in[2];
  const float* values = (const float*)d_in[3];
  const float* masks  = (const float*)d_in[4];
  float* out = (float*)d_out;

  char* ws = (char*)d_ws;
  size_t off = 0;
  auto alloc = [&](size_t bytes) -> void* {
    void* p = ws + off; off += (bytes + 255) & ~(size_t)255; return p;
  };
  u16* qT  = (u16*)alloc((size_t)N_PAD * D_KEY * 2);
  u16* kT  = (u16*)alloc((size_t)BANK_P * D_KEY * 2);
  u8*  vm8 = (u8*)alloc((size_t)M_PAD * BANK_P);
  u8*  E8  = (u8*)alloc((size_t)N_PAD * BANK_P);

  int nParts = 8;
  while (nParts > 1 && off + (size_t)nParts * M_PAD * LDCOL * 2 > ws_size) nParts >>= 1;
  u16* memC = (u16*)alloc((size_t)nParts * M_PAD * LDCOL * 2);

  prep<<<356, 256, 0, stream>>>(q_in, keys, qT, kT);

  const int vmBlocks = (M_PAD * (BANK_P / 16) + 255) / 256;   // 3952
  gemm_qk_vm<<<QK_BLOCKS + vmBlocks, 256, 0, stream>>>(qT, kT, E8, values, masks, vm8);

  gemm_pv<<<dim3(169 * nParts), 256, 0, stream>>>(vm8, E8, memC, nParts, (size_t)M_PAD * LDCOL);

  epilogue<<<(OBJ_N * 1024 * (N_TOK / 4) + 255) / 256, 256, 0, stream>>>(
      memC, q_out, out, nParts);
}

// Round 11
// 185.879 us; speedup vs baseline: 1.1990x; 1.0168x over previous
//
#include <hip/hip_runtime.h>
#include <hip/hip_bf16.h>

typedef unsigned short u16;
typedef unsigned char  u8;

#define D_KEY   128
#define BANK_N  9720
#define BANK_P  9728   /* 76*128 */
#define N_TOK   1620
#define N_PAD   1664   /* 13*128 */
#define OBJ_N   3
#define M_PAD   1664
#define LDCOL   1664
#define ONES_ROW 1539  /* vm row of 1.0 -> PV computes lsum as C row 1539 */
#define QK_SCALE 0.08838834764831845f
#define KITERS  76     /* BANK_P / 128 */
#define QK_BLOCKS 988  /* 13 * 76 */

typedef __bf16 bf16x8 __attribute__((ext_vector_type(8)));
typedef float  f32x4  __attribute__((ext_vector_type(4)));
typedef float  f32x16 __attribute__((ext_vector_type(16)));
typedef unsigned int u32x4 __attribute__((ext_vector_type(4)));
typedef int i32x8 __attribute__((ext_vector_type(8)));

__device__ __forceinline__ float bf2f(u16 u) {
  union { unsigned int i; float f; } v; v.i = ((unsigned int)u) << 16; return v.f;
}
__device__ __forceinline__ u16 f2bf(float f) {
  unsigned int x = __float_as_uint(f);
  unsigned int r = x + 0x7fffu + ((x >> 16) & 1u);  // RNE
  return (u16)(r >> 16);
}
__device__ __forceinline__ unsigned pack_fp8x4(float a, float b, float c, float d) {
  unsigned v = __builtin_amdgcn_cvt_pk_fp8_f32(a, b, 0, false);
  v = __builtin_amdgcn_cvt_pk_fp8_f32(c, d, v, true);
  return v;
}
__device__ __forceinline__ u8 f2fp8(float a) {
  return (u8)(__builtin_amdgcn_cvt_pk_fp8_f32(a, 0.f, 0, false) & 0xff);
}

__device__ __forceinline__ void load_lds16(const void* g, void* l) {
  __builtin_amdgcn_global_load_lds(
      (const __attribute__((address_space(1))) void*)g,
      (__attribute__((address_space(3))) void*)l, 16, 0, 0);
}

// ---- prep: qT transpose (0..51) + keys transpose (52..355) ----
__global__ void prep(const float* __restrict__ q, const float* __restrict__ keys,
                     u16* __restrict__ qT, u16* __restrict__ kT) {
  __shared__ float t[64][65];
  int b = blockIdx.x;
  const int tx = threadIdx.x & 63;
  const int ty = threadIdx.x >> 6;
  if (b < 52) {                                    // qT: [128][N_TOK] -> [N_PAD][128]
    const int bd = (b & 1) * 64;                   // d-tile
    const int bn = (b >> 1) * 64;                  // n-tile (26 tiles -> 1664 rows)
#pragma unroll
    for (int i = 0; i < 64; i += 4) {
      int d = bd + ty + i;
      int n = bn + tx;
      t[ty + i][tx] = (n < N_TOK) ? q[(size_t)d * N_TOK + n] : 0.f;
    }
    __syncthreads();
#pragma unroll
    for (int i = 0; i < 64; i += 4) {
      int r = ty + i;                              // n within tile
      qT[(size_t)(bn + r) * D_KEY + bd + tx] = f2bf(t[tx][r] * QK_SCALE);
    }
    return;
  }
  // keys transpose: 152 x 2 tiles
  b -= 52;
  const int bk = (b % 152) * 64;
  const int bd = (b / 152) * 64;
#pragma unroll
  for (int i = 0; i < 64; i += 4) {
    int d = bd + ty + i;
    int k = bk + tx;
    t[ty + i][tx] = (k < BANK_N) ? keys[(size_t)d * BANK_N + k] : 0.f;
  }
  __syncthreads();
#pragma unroll
  for (int i = 0; i < 64; i += 4) {
    int r = ty + i;
    kT[(size_t)(bk + r) * D_KEY + bd + tx] = f2bf(t[tx][r]);
  }
}

// ---- QK GEMM (blocks 0..987) + vm8 fp8 cast (blocks 988..4939) in ONE dispatch ----
__global__ void gemm_qk_vm(const u16* __restrict__ A, const u16* __restrict__ B,
                           u8* __restrict__ E8,
                           const float* __restrict__ values,
                           const float* __restrict__ masks,
                           u8* __restrict__ vm8)
{
  __shared__ __align__(16) u16 sbuf[8192];    // 16 KB: As 8K + Bs 8K; E8-stage aliases all

  if (blockIdx.x >= QK_BLOCKS) {
    // ---- vm8: fp8 cast, 16 bytes/thread (4x float4 loads = 64 B contiguous) ----
    const int NV = BANK_P / 16;                    // 608
    int idx = (blockIdx.x - QK_BLOCKS) * 256 + threadIdx.x;
    if (idx >= M_PAD * NV) return;
    int m = idx / NV;
    int k16 = (idx - m * NV) * 16;
    const bool ones = (m == ONES_ROW);
    const float* src = nullptr;
    if (m < 1536)          src = values + (size_t)m * BANK_N;
    else if (m < ONES_ROW) src = masks + (size_t)(m - 1536) * BANK_N;
    u32x4 outv;
#pragma unroll
    for (int c = 0; c < 4; c++) {
      int k4 = k16 + c * 4;
      float4 v = make_float4(0.f, 0.f, 0.f, 0.f);
      if (ones) {
        v.x = (k4     < BANK_N) ? 1.f : 0.f;
        v.y = (k4 + 1 < BANK_N) ? 1.f : 0.f;
        v.z = (k4 + 2 < BANK_N) ? 1.f : 0.f;
        v.w = (k4 + 3 < BANK_N) ? 1.f : 0.f;
      } else if (src) {
        if (k4 + 3 < BANK_N) v = *(const float4*)(src + k4);
        else {
          if (k4     < BANK_N) v.x = src[k4];
          if (k4 + 1 < BANK_N) v.y = src[k4 + 1];
          if (k4 + 2 < BANK_N) v.z = src[k4 + 2];
          if (k4 + 3 < BANK_N) v.w = src[k4 + 3];
        }
      }
      outv[c] = pack_fp8x4(v.x, v.y, v.z, v.w);
    }
    *(u32x4*)(vm8 + (size_t)m * BANK_P + k16) = outv;
    return;
  }

  // ---- QK GEMM: E8[n][k] = fp8(exp(qT.kT)); pad cols -> 0 ----
  u16* As = sbuf;
  u16* Bs = sbuf + 4096;

  const int tid  = threadIdx.x;
  const int wave = tid >> 6;
  const int lane = tid & 63;
  const int bn = blockIdx.x % 76, bm = blockIdx.x / 76;

  const u16* Abase = A + (size_t)bm * 128 * D_KEY;
  const u16* Bbase = B + (size_t)bn * 128 * D_KEY;

  const int r  = lane >> 2;
  const int c8 = (lane & 3) << 3;
  const int s0 = wave, s1 = wave + 4;

  f32x4 acc[4][4];
#pragma unroll
  for (int i = 0; i < 4; i++)
#pragma unroll
    for (int j = 0; j < 4; j++) acc[i][j] = (f32x4){0.f, 0.f, 0.f, 0.f};

  const int m_in = lane & 15;
  const int quad = lane >> 4;
  const int wm = (wave >> 1) * 64;
  const int wn = (wave & 1) * 64;

  for (int kt = 0; kt < D_KEY; kt += 32) {
    load_lds16(Abase + (size_t)(s0 * 16 + r) * D_KEY + kt + c8, &As[s0 * 512]);
    load_lds16(Abase + (size_t)(s1 * 16 + r) * D_KEY + kt + c8, &As[s1 * 512]);
    load_lds16(Bbase + (size_t)(s0 * 16 + r) * D_KEY + kt + c8, &Bs[s0 * 512]);
    load_lds16(Bbase + (size_t)(s1 * 16 + r) * D_KEY + kt + c8, &Bs[s1 * 512]);
    __syncthreads();

    bf16x8 af[4], bfr[4];
#pragma unroll
    for (int i = 0; i < 4; i++)
      af[i] = *(const bf16x8*)&As[(wm + i * 16 + m_in) * 32 + quad * 8];
#pragma unroll
    for (int j = 0; j < 4; j++)
      bfr[j] = *(const bf16x8*)&Bs[(wn + j * 16 + m_in) * 32 + quad * 8];
#pragma unroll
    for (int i = 0; i < 4; i++)
#pragma unroll
      for (int j = 0; j < 4; j++)
        acc[i][j] = __builtin_amdgcn_mfma_f32_16x16x32_bf16(af[i], bfr[j], acc[i][j], 0, 0, 0);
    __syncthreads();
  }

  // exp -> fp8, zero pad cols; stage 16KB in LDS; coalesced store
  u8* sb8 = (u8*)sbuf;
#pragma unroll
  for (int i = 0; i < 4; i++)
#pragma unroll
    for (int j = 0; j < 4; j++)
#pragma unroll
      for (int t = 0; t < 4; t++) {
        int row_l = wm + i * 16 + quad * 4 + t;   // D layout: col=lane&15, row=quad*4+t [m89]
        int col_l = wn + j * 16 + m_in;
        bool valid = (bn * 128 + col_l) < BANK_N;
        sb8[(row_l << 7) + col_l] = valid ? f2fp8(__expf(acc[i][j][t])) : (u8)0;
      }
  __syncthreads();

  for (int chunk = tid; chunk < 1024; chunk += 256) {
    int row = chunk >> 3;
    int cu  = (chunk & 7) << 4;
    u32x4 v = *(const u32x4*)&sb8[(row << 7) + cu];
    *(u32x4*)&E8[(size_t)(bm * 128 + row) * BANK_P + bn * 128 + cu] = v;
  }
}

// ---- PV GEMM (R11 = R10 resubmit): BK=64 / 32x32x64 MFMA / 32 KB dbuf with
// ONE barrier per iter. stage(t+1) targets the OTHER buffer ((t+1)&1), whose
// last reader was compute(t-1) -- guarded by the previous barrier. Iter:
// issue stage(t+1) -> ds_read+MFMA(t) -> vmcnt(0) (own stage loads, covered by
// ~400cy compute slack) -> barrier. Half the barriers of R9's B1/B2 scheme.
// LDS swizzle u' = u ^ ((row>>1)&3) (R9-verified); pre-swizzled global source
// with linear global_load_lds dest (rule #21).
__global__ __launch_bounds__(256, 4)
void gemm_pv(const u8* __restrict__ A, const u8* __restrict__ B,
             u16* __restrict__ memC, int nParts, size_t cPartStride)
{
  __shared__ __align__(16) u16 sbuf[16384];   // 32 KB: 2 x (A 8K + B 8K); C-stage aliases
  u8* const lds0 = (u8*)sbuf;

  const int tid  = threadIdx.x;
  const int wave = tid >> 6;
  const int lane = tid & 63;

  // T1 bijective XCD chunk swizzle (m204 form; handles gridDim.x % 8 != 0)
  const int bq = (int)gridDim.x >> 3, br = (int)gridDim.x & 7;
  const int xcd = blockIdx.x & 7, bj = blockIdx.x >> 3;
  int b = (xcd < br ? xcd * (bq + 1) : br * (bq + 1) + (xcd - br) * bq) + bj;

  int bz = b / 169;
  int rr = b - bz * 169;
  int gid = rr / 52;
  int rem = rr - gid * 52;
  int width = (gid < 3) ? 4 : 1;
  int bm = rem / width;
  int bn = gid * 4 + (rem - bm * width);

  // uneven K-split over 128-wide super-iters; BK=64 doubles the iter count
  const int base = KITERS / nParts;
  const int remP = KITERS - base * nParts;
  const int nt128 = base + (bz < remP ? 1 : 0);
  const int itbeg = bz * base + (bz < remP ? bz : remP);
  const int kbeg  = itbeg * 128;
  const int kN    = nt128 * 2;                // #BK=64 iters (>= 18 at nParts=8)

  const u8* Abase = A + (size_t)bm * 128 * BANK_P;
  const u8* Bbase = B + (size_t)bn * 128 * BANK_P;

  f32x16 acc[2][2];
#pragma unroll
  for (int i = 0; i < 2; i++)
#pragma unroll
    for (int j = 0; j < 2; j++)
#pragma unroll
      for (int r = 0; r < 16; r++) acc[i][j][r] = 0.f;

  const int l31  = lane & 31;
  const int h    = lane >> 5;                 // k-half of the lane
  const int wm   = (wave >> 1) * 64;
  const int wn   = (wave & 1) * 64;

  // stage-side per-lane source swizzle: lane writes LDS unit (rowl, lane&3);
  // source global unit = (lane&3) ^ ((rowl>>1)&3)
  const int srow0 = wave * 32 + (lane >> 2);  // s=0 row; s=1 adds 16
  const int sswz0 = ((lane & 3) ^ ((srow0 >> 1) & 3)) << 4;
  const int srow1 = srow0 + 16;
  const int sswz1 = ((lane & 3) ^ ((srow1 >> 1) & 3)) << 4;
  const size_t soffA0 = (size_t)srow0 * BANK_P + sswz0;
  const size_t soffA1 = (size_t)srow1 * BANK_P + sswz1;

  // stage one BK=64 tile (A 8K + B 8K) into buffer q; 4 loads/wave
  auto stage = [&](int t64, int q) {
    const int kt = kbeg + t64 * 64;
    u8* dst = lds0 + q * 16384 + wave * 2048;
    load_lds16(Abase + soffA0 + kt, dst);
    load_lds16(Abase + soffA1 + kt, dst + 1024);
    load_lds16(Bbase + soffA0 + kt, dst + 8192);
    load_lds16(Bbase + soffA1 + kt, dst + 8192 + 1024);
  };

  // prologue: tile 0 into buf0, drain, barrier
  stage(0, 0);
  asm volatile("s_waitcnt vmcnt(0)" ::: "memory");
  __builtin_amdgcn_s_barrier();
  __builtin_amdgcn_sched_barrier(0);

  for (int t = 0; t < kN; ++t) {
    // issue next tile into the OTHER buffer first (its last reader was
    // compute(t-1), guarded by the previous barrier)
    if (t + 1 < kN) stage(t + 1, (t + 1) & 1);

    const u8* As8 = lds0 + (t & 1) * 16384;
    const u8* Bs8 = As8 + 8192;

    __builtin_amdgcn_s_setprio(1);
    i32x8 a8[2], b8[2];
#pragma unroll
    for (int m = 0; m < 2; m++) {
      const int row = wm + m * 32 + l31;
      const int s = (row >> 1) & 3;
      const u8* p = As8 + row * 64;
      u32x4 lo = *(const u32x4*)(p + (((2 * h)     ^ s) << 4));
      u32x4 hi = *(const u32x4*)(p + (((2 * h + 1) ^ s) << 4));
      a8[m] = (i32x8){(int)lo[0], (int)lo[1], (int)lo[2], (int)lo[3],
                      (int)hi[0], (int)hi[1], (int)hi[2], (int)hi[3]};
    }
#pragma unroll
    for (int n = 0; n < 2; n++) {
      const int row = wn + n * 32 + l31;
      const int s = (row >> 1) & 3;
      const u8* p = Bs8 + row * 64;
      u32x4 lo = *(const u32x4*)(p + (((2 * h)     ^ s) << 4));
      u32x4 hi = *(const u32x4*)(p + (((2 * h + 1) ^ s) << 4));
      b8[n] = (i32x8){(int)lo[0], (int)lo[1], (int)lo[2], (int)lo[3],
                      (int)hi[0], (int)hi[1], (int)hi[2], (int)hi[3]};
    }
#pragma unroll
    for (int n = 0; n < 2; n++)
#pragma unroll
      for (int m = 0; m < 2; m++)
        acc[m][n] = __builtin_amdgcn_mfma_scale_f32_32x32x64_f8f6f4(
            a8[m], b8[n], acc[m][n], 0, 0,           // cbsz=fp8, blgp=fp8
            0, 0x7f7f7f7f, 0, 0x7f7f7f7f);           // unit scales (E8M0 127 = x1)
    __builtin_amdgcn_s_setprio(0);

    if (t + 1 >= kN) break;

    // retire own stage(t+1) loads (issued ~compute-duration ago), then sync:
    // after the barrier every wave's stage(t+1) is certified landed.
    __builtin_amdgcn_sched_barrier(0);
    asm volatile("s_waitcnt vmcnt(0)" ::: "memory");
    __builtin_amdgcn_s_barrier();
    __builtin_amdgcn_sched_barrier(0);
  }

  __syncthreads();

  // C-stage in two 16-KB halves (rows 0-63 by waves 0,1; rows 64-127 by 2,3)
  u16* Cg = memC + (size_t)bz * cPartStride;
#pragma unroll
  for (int hh = 0; hh < 2; hh++) {
    __syncthreads();
    if ((wave >> 1) == hh) {
#pragma unroll
      for (int m = 0; m < 2; m++)
#pragma unroll
        for (int n = 0; n < 2; n++)
#pragma unroll
          for (int r = 0; r < 16; r++) {
            int row_l = m * 32 + (r & 3) + 8 * (r >> 2) + 4 * h;  // 0..63
            int col_l = (wave & 1) * 64 + n * 32 + l31;
            sbuf[(row_l << 7) + col_l] = f2bf(acc[m][n][r]);
          }
    }
    __syncthreads();
    for (int chunk = tid; chunk < 1024; chunk += 256) {
      int row = chunk >> 4;                         // 0..63
      int cu  = (chunk & 15) << 3;
      u32x4 v = *(const u32x4*)&sbuf[(row << 7) + cu];
      *(u32x4*)&Cg[(size_t)(bm * 128 + hh * 64 + row) * LDCOL + bn * 128 + cu] = v;
    }
  }
}

// ---- epilogue: vec4 over n; lsum from memC row ONES_ROW (L2/L3-broadcast) ----
__global__ void epilogue(const u16* __restrict__ memC, const float* __restrict__ q_out,
                         float* __restrict__ out, int nParts) {
  const int NV = N_TOK / 4;                     // 405
  int idx = blockIdx.x * 256 + threadIdx.x;
  if (idx >= OBJ_N * 1024 * NV) return;
  int n4 = (idx % NV) * 4;
  int t = idx / NV;
  int c = t & 1023;
  int o = t >> 10;
  const size_t ps = (size_t)M_PAD * LDCOL;

  const u16* lbase = memC + (size_t)ONES_ROW * LDCOL + n4;
  float4 l = make_float4(0.f, 0.f, 0.f, 0.f);
  for (int z = 0; z < nParts; z++) {
    ushort4 v = *(const ushort4*)(lbase + z * ps);
    l.x += bf2f(v.x); l.y += bf2f(v.y); l.z += bf2f(v.z); l.w += bf2f(v.w);
  }

  size_t rowoff = (c < 512) ? (size_t)(o * 512 + c) * LDCOL
                            : (size_t)(1536 + o) * LDCOL;
  const u16* base = memC + rowoff + n4;
  float4 s = make_float4(0.f, 0.f, 0.f, 0.f);
  for (int z = 0; z < nParts; z++) {
    ushort4 v = *(const ushort4*)(base + z * ps);
    s.x += bf2f(v.x); s.y += bf2f(v.y); s.z += bf2f(v.z); s.w += bf2f(v.w);
  }
  float4 rv;
  float ix = 1.f / l.x, iy = 1.f / l.y, iz = 1.f / l.z, iw = 1.f / l.w;
  if (c < 512) {
    rv.x = s.x * ix; rv.y = s.y * iy; rv.z = s.z * iz; rv.w = s.w * iw;
  } else {
    float4 q = *(const float4*)(q_out + (size_t)(o * 512 + (c - 512)) * N_TOK + n4);
    rv.x = q.x * s.x * ix; rv.y = q.y * s.y * iy;
    rv.z = q.z * s.z * iz; rv.w = q.w * s.w * iw;
  }
  *(float4*)(out + (size_t)(o * 1024 + c) * N_TOK + n4) = rv;
}

extern "C" void kernel_launch(void* const* d_in, const int* in_sizes, int n_in,
                              void* d_out, int out_size, void* d_ws, size_t ws_size,
                              hipStream_t stream) {
  const float* keys   = (const float*)d_in[0];
  const float* q_in   = (const float*)d_in[1];
  const float* q_out  = (const float*)d_in[2];
  const float* values = (const float*)d_in[3];
  const float* masks  = (const float*)d_in[4];
  float* out = (float*)d_out;

  char* ws = (char*)d_ws;
  size_t off = 0;
  auto alloc = [&](size_t bytes) -> void* {
    void* p = ws + off; off += (bytes + 255) & ~(size_t)255; return p;
  };
  u16* qT  = (u16*)alloc((size_t)N_PAD * D_KEY * 2);
  u16* kT  = (u16*)alloc((size_t)BANK_P * D_KEY * 2);
  u8*  vm8 = (u8*)alloc((size_t)M_PAD * BANK_P);
  u8*  E8  = (u8*)alloc((size_t)N_PAD * BANK_P);

  int nParts = 8;
  while (nParts > 1 && off + (size_t)nParts * M_PAD * LDCOL * 2 > ws_size) nParts >>= 1;
  u16* memC = (u16*)alloc((size_t)nParts * M_PAD * LDCOL * 2);

  prep<<<356, 256, 0, stream>>>(q_in, keys, qT, kT);

  const int vmBlocks = (M_PAD * (BANK_P / 16) + 255) / 256;   // 3952
  gemm_qk_vm<<<QK_BLOCKS + vmBlocks, 256, 0, stream>>>(qT, kT, E8, values, masks, vm8);

  gemm_pv<<<dim3(169 * nParts), 256, 0, stream>>>(vm8, E8, memC, nParts, (size_t)M_PAD * LDCOL);

  epilogue<<<(OBJ_N * 1024 * (N_TOK / 4) + 255) / 256, 256, 0, stream>>>(
      memC, q_out, out, nParts);
}

// Round 12
// 175.485 us; speedup vs baseline: 1.2700x; 1.0592x over previous
//
#include <hip/hip_runtime.h>
#include <hip/hip_bf16.h>

typedef unsigned short u16;
typedef unsigned char  u8;

#define D_KEY   128
#define BANK_N  9720
#define BANK_P  9728   /* 76*128 */
#define N_TOK   1620
#define N_PAD   1664   /* 13*128 */
#define OBJ_N   3
#define M_PAD   1664
#define LDCOL   1664
#define ONES_ROW 1539  /* vm row of 1.0 -> PV computes lsum as C row 1539 */
#define QK_SCALE 0.08838834764831845f
#define KITERS  76     /* BANK_P / 128 */
#define QK_BLOCKS 988  /* 13 * 76 */

typedef __bf16 bf16x8 __attribute__((ext_vector_type(8)));
typedef float  f32x4  __attribute__((ext_vector_type(4)));
typedef float  f32x16 __attribute__((ext_vector_type(16)));
typedef unsigned int u32x4 __attribute__((ext_vector_type(4)));
typedef int i32x8 __attribute__((ext_vector_type(8)));

__device__ __forceinline__ float bf2f(u16 u) {
  union { unsigned int i; float f; } v; v.i = ((unsigned int)u) << 16; return v.f;
}
__device__ __forceinline__ u16 f2bf(float f) {
  unsigned int x = __float_as_uint(f);
  unsigned int r = x + 0x7fffu + ((x >> 16) & 1u);  // RNE
  return (u16)(r >> 16);
}
__device__ __forceinline__ unsigned pack_fp8x4(float a, float b, float c, float d) {
  unsigned v = __builtin_amdgcn_cvt_pk_fp8_f32(a, b, 0, false);
  v = __builtin_amdgcn_cvt_pk_fp8_f32(c, d, v, true);
  return v;
}
__device__ __forceinline__ u8 f2fp8(float a) {
  return (u8)(__builtin_amdgcn_cvt_pk_fp8_f32(a, 0.f, 0, false) & 0xff);
}

__device__ __forceinline__ void load_lds16(const void* g, void* l) {
  __builtin_amdgcn_global_load_lds(
      (const __attribute__((address_space(1))) void*)g,
      (__attribute__((address_space(3))) void*)l, 16, 0, 0);
}

// ---- prep: qT transpose (0..51) + keys transpose (52..355) ----
__global__ void prep(const float* __restrict__ q, const float* __restrict__ keys,
                     u16* __restrict__ qT, u16* __restrict__ kT) {
  __shared__ float t[64][65];
  int b = blockIdx.x;
  const int tx = threadIdx.x & 63;
  const int ty = threadIdx.x >> 6;
  if (b < 52) {                                    // qT: [128][N_TOK] -> [N_PAD][128]
    const int bd = (b & 1) * 64;                   // d-tile
    const int bn = (b >> 1) * 64;                  // n-tile (26 tiles -> 1664 rows)
#pragma unroll
    for (int i = 0; i < 64; i += 4) {
      int d = bd + ty + i;
      int n = bn + tx;
      t[ty + i][tx] = (n < N_TOK) ? q[(size_t)d * N_TOK + n] : 0.f;
    }
    __syncthreads();
#pragma unroll
    for (int i = 0; i < 64; i += 4) {
      int r = ty + i;                              // n within tile
      qT[(size_t)(bn + r) * D_KEY + bd + tx] = f2bf(t[tx][r] * QK_SCALE);
    }
    return;
  }
  // keys transpose: 152 x 2 tiles
  b -= 52;
  const int bk = (b % 152) * 64;
  const int bd = (b / 152) * 64;
#pragma unroll
  for (int i = 0; i < 64; i += 4) {
    int d = bd + ty + i;
    int k = bk + tx;
    t[ty + i][tx] = (k < BANK_N) ? keys[(size_t)d * BANK_N + k] : 0.f;
  }
  __syncthreads();
#pragma unroll
  for (int i = 0; i < 64; i += 4) {
    int r = ty + i;
    kT[(size_t)(bk + r) * D_KEY + bd + tx] = f2bf(t[tx][r]);
  }
}

// ---- QK GEMM (blocks 0..987) + vm8 fp8 cast (blocks 988..4939) in ONE dispatch ----
__global__ void gemm_qk_vm(const u16* __restrict__ A, const u16* __restrict__ B,
                           u8* __restrict__ E8,
                           const float* __restrict__ values,
                           const float* __restrict__ masks,
                           u8* __restrict__ vm8)
{
  __shared__ __align__(16) u16 sbuf[8192];    // 16 KB: As 8K + Bs 8K; E8-stage aliases all

  if (blockIdx.x >= QK_BLOCKS) {
    // ---- vm8: fp8 cast, 16 bytes/thread (4x float4 loads = 64 B contiguous) ----
    const int NV = BANK_P / 16;                    // 608
    int idx = (blockIdx.x - QK_BLOCKS) * 256 + threadIdx.x;
    if (idx >= M_PAD * NV) return;
    int m = idx / NV;
    int k16 = (idx - m * NV) * 16;
    const bool ones = (m == ONES_ROW);
    const float* src = nullptr;
    if (m < 1536)          src = values + (size_t)m * BANK_N;
    else if (m < ONES_ROW) src = masks + (size_t)(m - 1536) * BANK_N;
    u32x4 outv;
#pragma unroll
    for (int c = 0; c < 4; c++) {
      int k4 = k16 + c * 4;
      float4 v = make_float4(0.f, 0.f, 0.f, 0.f);
      if (ones) {
        v.x = (k4     < BANK_N) ? 1.f : 0.f;
        v.y = (k4 + 1 < BANK_N) ? 1.f : 0.f;
        v.z = (k4 + 2 < BANK_N) ? 1.f : 0.f;
        v.w = (k4 + 3 < BANK_N) ? 1.f : 0.f;
      } else if (src) {
        if (k4 + 3 < BANK_N) v = *(const float4*)(src + k4);
        else {
          if (k4     < BANK_N) v.x = src[k4];
          if (k4 + 1 < BANK_N) v.y = src[k4 + 1];
          if (k4 + 2 < BANK_N) v.z = src[k4 + 2];
          if (k4 + 3 < BANK_N) v.w = src[k4 + 3];
        }
      }
      outv[c] = pack_fp8x4(v.x, v.y, v.z, v.w);
    }
    *(u32x4*)(vm8 + (size_t)m * BANK_P + k16) = outv;
    return;
  }

  // ---- QK GEMM: E8[n][k] = fp8(exp(qT.kT)); pad cols -> 0 ----
  u16* As = sbuf;
  u16* Bs = sbuf + 4096;

  const int tid  = threadIdx.x;
  const int wave = tid >> 6;
  const int lane = tid & 63;
  const int bn = blockIdx.x % 76, bm = blockIdx.x / 76;

  const u16* Abase = A + (size_t)bm * 128 * D_KEY;
  const u16* Bbase = B + (size_t)bn * 128 * D_KEY;

  const int r  = lane >> 2;
  const int c8 = (lane & 3) << 3;
  const int s0 = wave, s1 = wave + 4;

  f32x4 acc[4][4];
#pragma unroll
  for (int i = 0; i < 4; i++)
#pragma unroll
    for (int j = 0; j < 4; j++) acc[i][j] = (f32x4){0.f, 0.f, 0.f, 0.f};

  const int m_in = lane & 15;
  const int quad = lane >> 4;
  const int wm = (wave >> 1) * 64;
  const int wn = (wave & 1) * 64;

  for (int kt = 0; kt < D_KEY; kt += 32) {
    load_lds16(Abase + (size_t)(s0 * 16 + r) * D_KEY + kt + c8, &As[s0 * 512]);
    load_lds16(Abase + (size_t)(s1 * 16 + r) * D_KEY + kt + c8, &As[s1 * 512]);
    load_lds16(Bbase + (size_t)(s0 * 16 + r) * D_KEY + kt + c8, &Bs[s0 * 512]);
    load_lds16(Bbase + (size_t)(s1 * 16 + r) * D_KEY + kt + c8, &Bs[s1 * 512]);
    __syncthreads();

    bf16x8 af[4], bfr[4];
#pragma unroll
    for (int i = 0; i < 4; i++)
      af[i] = *(const bf16x8*)&As[(wm + i * 16 + m_in) * 32 + quad * 8];
#pragma unroll
    for (int j = 0; j < 4; j++)
      bfr[j] = *(const bf16x8*)&Bs[(wn + j * 16 + m_in) * 32 + quad * 8];
#pragma unroll
    for (int i = 0; i < 4; i++)
#pragma unroll
      for (int j = 0; j < 4; j++)
        acc[i][j] = __builtin_amdgcn_mfma_f32_16x16x32_bf16(af[i], bfr[j], acc[i][j], 0, 0, 0);
    __syncthreads();
  }

  // exp -> fp8, zero pad cols; stage 16KB in LDS; coalesced store
  u8* sb8 = (u8*)sbuf;
#pragma unroll
  for (int i = 0; i < 4; i++)
#pragma unroll
    for (int j = 0; j < 4; j++)
#pragma unroll
      for (int t = 0; t < 4; t++) {
        int row_l = wm + i * 16 + quad * 4 + t;   // D layout: col=lane&15, row=quad*4+t [m89]
        int col_l = wn + j * 16 + m_in;
        bool valid = (bn * 128 + col_l) < BANK_N;
        sb8[(row_l << 7) + col_l] = valid ? f2fp8(__expf(acc[i][j][t])) : (u8)0;
      }
  __syncthreads();

  for (int chunk = tid; chunk < 1024; chunk += 256) {
    int row = chunk >> 3;
    int cu  = (chunk & 7) << 4;
    u32x4 v = *(const u32x4*)&sb8[(row << 7) + cu];
    *(u32x4*)&E8[(size_t)(bm * 128 + row) * BANK_P + bn * 128 + cu] = v;
  }
}

// ---- PV GEMM (R12 = R11 structure, nParts=4): BK=64 / 32x32x64 MFMA / 32 KB
// dbuf, ONE barrier per iter. stage(t+1) targets the OTHER buffer ((t+1)&1),
// last read by compute(t-1) and guarded by the previous barrier. Iter:
// issue stage(t+1) -> ds_read+MFMA(t) -> vmcnt(0) (covered by compute slack)
// -> barrier. nParts=4: 676 blocks, 38 iters/block -- halves C-writes
// (43->21.6 MB) and epilogue part-reads; R3-vs-R4 residual ledger says the
// nParts=8 split-K tax is ~9us outside pv. LDS swizzle u' = u ^ ((row>>1)&3)
// (R9-verified); pre-swizzled global source, linear gload_lds dest (rule #21).
__global__ __launch_bounds__(256, 4)
void gemm_pv(const u8* __restrict__ A, const u8* __restrict__ B,
             u16* __restrict__ memC, int nParts, size_t cPartStride)
{
  __shared__ __align__(16) u16 sbuf[16384];   // 32 KB: 2 x (A 8K + B 8K); C-stage aliases
  u8* const lds0 = (u8*)sbuf;

  const int tid  = threadIdx.x;
  const int wave = tid >> 6;
  const int lane = tid & 63;

  // T1 bijective XCD chunk swizzle (m204 form; handles gridDim.x % 8 != 0)
  const int bq = (int)gridDim.x >> 3, br = (int)gridDim.x & 7;
  const int xcd = blockIdx.x & 7, bj = blockIdx.x >> 3;
  int b = (xcd < br ? xcd * (bq + 1) : br * (bq + 1) + (xcd - br) * bq) + bj;

  int bz = b / 169;
  int rr = b - bz * 169;
  int gid = rr / 52;
  int rem = rr - gid * 52;
  int width = (gid < 3) ? 4 : 1;
  int bm = rem / width;
  int bn = gid * 4 + (rem - bm * width);

  // uneven K-split over 128-wide super-iters; BK=64 doubles the iter count
  const int base = KITERS / nParts;
  const int remP = KITERS - base * nParts;
  const int nt128 = base + (bz < remP ? 1 : 0);
  const int itbeg = bz * base + (bz < remP ? bz : remP);
  const int kbeg  = itbeg * 128;
  const int kN    = nt128 * 2;                // #BK=64 iters (38 at nParts=4)

  const u8* Abase = A + (size_t)bm * 128 * BANK_P;
  const u8* Bbase = B + (size_t)bn * 128 * BANK_P;

  f32x16 acc[2][2];
#pragma unroll
  for (int i = 0; i < 2; i++)
#pragma unroll
    for (int j = 0; j < 2; j++)
#pragma unroll
      for (int r = 0; r < 16; r++) acc[i][j][r] = 0.f;

  const int l31  = lane & 31;
  const int h    = lane >> 5;                 // k-half of the lane
  const int wm   = (wave >> 1) * 64;
  const int wn   = (wave & 1) * 64;

  // stage-side per-lane source swizzle: lane writes LDS unit (rowl, lane&3);
  // source global unit = (lane&3) ^ ((rowl>>1)&3)
  const int srow0 = wave * 32 + (lane >> 2);  // s=0 row; s=1 adds 16
  const int sswz0 = ((lane & 3) ^ ((srow0 >> 1) & 3)) << 4;
  const int srow1 = srow0 + 16;
  const int sswz1 = ((lane & 3) ^ ((srow1 >> 1) & 3)) << 4;
  const size_t soffA0 = (size_t)srow0 * BANK_P + sswz0;
  const size_t soffA1 = (size_t)srow1 * BANK_P + sswz1;

  // stage one BK=64 tile (A 8K + B 8K) into buffer q; 4 loads/wave
  auto stage = [&](int t64, int q) {
    const int kt = kbeg + t64 * 64;
    u8* dst = lds0 + q * 16384 + wave * 2048;
    load_lds16(Abase + soffA0 + kt, dst);
    load_lds16(Abase + soffA1 + kt, dst + 1024);
    load_lds16(Bbase + soffA0 + kt, dst + 8192);
    load_lds16(Bbase + soffA1 + kt, dst + 8192 + 1024);
  };

  // prologue: tile 0 into buf0, drain, barrier
  stage(0, 0);
  asm volatile("s_waitcnt vmcnt(0)" ::: "memory");
  __builtin_amdgcn_s_barrier();
  __builtin_amdgcn_sched_barrier(0);

  for (int t = 0; t < kN; ++t) {
    // issue next tile into the OTHER buffer first (its last reader was
    // compute(t-1), guarded by the previous barrier)
    if (t + 1 < kN) stage(t + 1, (t + 1) & 1);

    const u8* As8 = lds0 + (t & 1) * 16384;
    const u8* Bs8 = As8 + 8192;

    __builtin_amdgcn_s_setprio(1);
    i32x8 a8[2], b8[2];
#pragma unroll
    for (int m = 0; m < 2; m++) {
      const int row = wm + m * 32 + l31;
      const int s = (row >> 1) & 3;
      const u8* p = As8 + row * 64;
      u32x4 lo = *(const u32x4*)(p + (((2 * h)     ^ s) << 4));
      u32x4 hi = *(const u32x4*)(p + (((2 * h + 1) ^ s) << 4));
      a8[m] = (i32x8){(int)lo[0], (int)lo[1], (int)lo[2], (int)lo[3],
                      (int)hi[0], (int)hi[1], (int)hi[2], (int)hi[3]};
    }
#pragma unroll
    for (int n = 0; n < 2; n++) {
      const int row = wn + n * 32 + l31;
      const int s = (row >> 1) & 3;
      const u8* p = Bs8 + row * 64;
      u32x4 lo = *(const u32x4*)(p + (((2 * h)     ^ s) << 4));
      u32x4 hi = *(const u32x4*)(p + (((2 * h + 1) ^ s) << 4));
      b8[n] = (i32x8){(int)lo[0], (int)lo[1], (int)lo[2], (int)lo[3],
                      (int)hi[0], (int)hi[1], (int)hi[2], (int)hi[3]};
    }
#pragma unroll
    for (int n = 0; n < 2; n++)
#pragma unroll
      for (int m = 0; m < 2; m++)
        acc[m][n] = __builtin_amdgcn_mfma_scale_f32_32x32x64_f8f6f4(
            a8[m], b8[n], acc[m][n], 0, 0,           // cbsz=fp8, blgp=fp8
            0, 0x7f7f7f7f, 0, 0x7f7f7f7f);           // unit scales (E8M0 127 = x1)
    __builtin_amdgcn_s_setprio(0);

    if (t + 1 >= kN) break;

    // retire own stage(t+1) loads (issued ~compute-duration ago), then sync:
    // after the barrier every wave's stage(t+1) is certified landed.
    __builtin_amdgcn_sched_barrier(0);
    asm volatile("s_waitcnt vmcnt(0)" ::: "memory");
    __builtin_amdgcn_s_barrier();
    __builtin_amdgcn_sched_barrier(0);
  }

  __syncthreads();

  // C-stage in two 16-KB halves (rows 0-63 by waves 0,1; rows 64-127 by 2,3)
  u16* Cg = memC + (size_t)bz * cPartStride;
#pragma unroll
  for (int hh = 0; hh < 2; hh++) {
    __syncthreads();
    if ((wave >> 1) == hh) {
#pragma unroll
      for (int m = 0; m < 2; m++)
#pragma unroll
        for (int n = 0; n < 2; n++)
#pragma unroll
          for (int r = 0; r < 16; r++) {
            int row_l = m * 32 + (r & 3) + 8 * (r >> 2) + 4 * h;  // 0..63
            int col_l = (wave & 1) * 64 + n * 32 + l31;
            sbuf[(row_l << 7) + col_l] = f2bf(acc[m][n][r]);
          }
    }
    __syncthreads();
    for (int chunk = tid; chunk < 1024; chunk += 256) {
      int row = chunk >> 4;                         // 0..63
      int cu  = (chunk & 15) << 3;
      u32x4 v = *(const u32x4*)&sbuf[(row << 7) + cu];
      *(u32x4*)&Cg[(size_t)(bm * 128 + hh * 64 + row) * LDCOL + bn * 128 + cu] = v;
    }
  }
}

// ---- epilogue: vec4 over n; lsum from memC row ONES_ROW (L2/L3-broadcast) ----
__global__ void epilogue(const u16* __restrict__ memC, const float* __restrict__ q_out,
                         float* __restrict__ out, int nParts) {
  const int NV = N_TOK / 4;                     // 405
  int idx = blockIdx.x * 256 + threadIdx.x;
  if (idx >= OBJ_N * 1024 * NV) return;
  int n4 = (idx % NV) * 4;
  int t = idx / NV;
  int c = t & 1023;
  int o = t >> 10;
  const size_t ps = (size_t)M_PAD * LDCOL;

  const u16* lbase = memC + (size_t)ONES_ROW * LDCOL + n4;
  float4 l = make_float4(0.f, 0.f, 0.f, 0.f);
  for (int z = 0; z < nParts; z++) {
    ushort4 v = *(const ushort4*)(lbase + z * ps);
    l.x += bf2f(v.x); l.y += bf2f(v.y); l.z += bf2f(v.z); l.w += bf2f(v.w);
  }

  size_t rowoff = (c < 512) ? (size_t)(o * 512 + c) * LDCOL
                            : (size_t)(1536 + o) * LDCOL;
  const u16* base = memC + rowoff + n4;
  float4 s = make_float4(0.f, 0.f, 0.f, 0.f);
  for (int z = 0; z < nParts; z++) {
    ushort4 v = *(const ushort4*)(base + z * ps);
    s.x += bf2f(v.x); s.y += bf2f(v.y); s.z += bf2f(v.z); s.w += bf2f(v.w);
  }
  float4 rv;
  float ix = 1.f / l.x, iy = 1.f / l.y, iz = 1.f / l.z, iw = 1.f / l.w;
  if (c < 512) {
    rv.x = s.x * ix; rv.y = s.y * iy; rv.z = s.z * iz; rv.w = s.w * iw;
  } else {
    float4 q = *(const float4*)(q_out + (size_t)(o * 512 + (c - 512)) * N_TOK + n4);
    rv.x = q.x * s.x * ix; rv.y = q.y * s.y * iy;
    rv.z = q.z * s.z * iz; rv.w = q.w * s.w * iw;
  }
  *(float4*)(out + (size_t)(o * 1024 + c) * N_TOK + n4) = rv;
}

extern "C" void kernel_launch(void* const* d_in, const int* in_sizes, int n_in,
                              void* d_out, int out_size, void* d_ws, size_t ws_size,
                              hipStream_t stream) {
  const float* keys   = (const float*)d_in[0];
  const float* q_in   = (const float*)d_in[1];
  const float* q_out  = (const float*)d_in[2];
  const float* values = (const float*)d_in[3];
  const float* masks  = (const float*)d_in[4];
  float* out = (float*)d_out;

  char* ws = (char*)d_ws;
  size_t off = 0;
  auto alloc = [&](size_t bytes) -> void* {
    void* p = ws + off; off += (bytes + 255) & ~(size_t)255; return p;
  };
  u16* qT  = (u16*)alloc((size_t)N_PAD * D_KEY * 2);
  u16* kT  = (u16*)alloc((size_t)BANK_P * D_KEY * 2);
  u8*  vm8 = (u8*)alloc((size_t)M_PAD * BANK_P);
  u8*  E8  = (u8*)alloc((size_t)N_PAD * BANK_P);

  int nParts = 4;                              // R12: split-K 8->4 (see pv comment)
  while (nParts > 1 && off + (size_t)nParts * M_PAD * LDCOL * 2 > ws_size) nParts >>= 1;
  u16* memC = (u16*)alloc((size_t)nParts * M_PAD * LDCOL * 2);

  prep<<<356, 256, 0, stream>>>(q_in, keys, qT, kT);

  const int vmBlocks = (M_PAD * (BANK_P / 16) + 255) / 256;   // 3952
  gemm_qk_vm<<<QK_BLOCKS + vmBlocks, 256, 0, stream>>>(qT, kT, E8, values, masks, vm8);

  gemm_pv<<<dim3(169 * nParts), 256, 0, stream>>>(vm8, E8, memC, nParts, (size_t)M_PAD * LDCOL);

  epilogue<<<(OBJ_N * 1024 * (N_TOK / 4) + 255) / 256, 256, 0, stream>>>(
      memC, q_out, out, nParts);
}